// Round 1
// baseline (744.629 us; speedup 1.0000x reference)
//
#include <hip/hip_runtime.h>

#define D 128
#define FFN 512
#define BOT 64

// ---------------- CSR build ----------------

__global__ __launch_bounds__(256) void k_zero(int* p, int n) {
  int i = blockIdx.x * 256 + threadIdx.x;
  if (i < n) p[i] = 0;
}

__global__ __launch_bounds__(256) void k_hist(const int* __restrict__ ei, int* __restrict__ cnt, int nE) {
  int i = blockIdx.x * 256 + threadIdx.x;
  if (i < nE) atomicAdd(&cnt[ei[nE + i]], 1);   // dst = ei[E + i]
}

__global__ __launch_bounds__(256) void k_norm(const int* __restrict__ cnt, float* __restrict__ nrm, int n) {
  int i = blockIdx.x * 256 + threadIdx.x;
  if (i < n) nrm[i] = rsqrtf((float)cnt[i] + 1.0f);
}

__global__ __launch_bounds__(256) void k_scan1(const int* __restrict__ cnt, int* __restrict__ part,
                                               int* __restrict__ bsum, int n) {
  __shared__ int s[256];
  int t = threadIdx.x;
  int i = blockIdx.x * 256 + t;
  int v = (i < n) ? cnt[i] : 0;
  s[t] = v;
  __syncthreads();
  for (int d = 1; d < 256; d <<= 1) {
    int add = (t >= d) ? s[t - d] : 0;
    __syncthreads();
    s[t] += add;
    __syncthreads();
  }
  if (i < n) part[i] = s[t] - v;          // exclusive within block
  if (t == 255) bsum[blockIdx.x] = s[255]; // block total
}

__global__ __launch_bounds__(256) void k_scan2(const int* __restrict__ bsum, int* __restrict__ boff, int nb) {
  __shared__ int s[256];
  int t = threadIdx.x;
  int v = (t < nb) ? bsum[t] : 0;
  s[t] = v;
  __syncthreads();
  for (int d = 1; d < 256; d <<= 1) {
    int add = (t >= d) ? s[t - d] : 0;
    __syncthreads();
    s[t] += add;
    __syncthreads();
  }
  boff[t] = s[t] - v;                     // exclusive block offsets
}

__global__ __launch_bounds__(256) void k_scan3(const int* __restrict__ part, const int* __restrict__ boff,
                                               int* __restrict__ rowptr, int* __restrict__ cursor,
                                               int n, int nE) {
  int i = blockIdx.x * 256 + threadIdx.x;
  if (i < n) {
    int r = part[i] + boff[i >> 8];
    rowptr[i] = r;
    cursor[i] = r;
  }
  if (i == 0) rowptr[n] = nE;
}

__global__ __launch_bounds__(256) void k_fill(const int* __restrict__ ei, int* __restrict__ cursor,
                                              int* __restrict__ col, int nE) {
  int i = blockIdx.x * 256 + threadIdx.x;
  if (i < nE) {
    int s = ei[i];
    int d2 = ei[nE + i];
    int pos = atomicAdd(&cursor[d2], 1);
    col[pos] = s;
  }
}

// ---------------- per-layer: Y = (X @ W) * norm[row] ----------------
// block: 64 rows x 128 cols, 256 threads, thread tile 4x8

__global__ __launch_bounds__(256) void k_xw(const float* __restrict__ X, const float* __restrict__ W,
                                            const float* __restrict__ nrm, float* __restrict__ Y, int n) {
  __shared__ float Xs[64][132];
  __shared__ float Ws[128 * 128];
  int t = threadIdx.x;
  int rb = blockIdx.x * 64;

  #pragma unroll
  for (int m = 0; m < 16; ++m)
    ((float4*)Ws)[m * 256 + t] = ((const float4*)W)[m * 256 + t];

  #pragma unroll
  for (int m = 0; m < 8; ++m) {
    int i4 = m * 256 + t;
    int r = i4 >> 5, k4 = i4 & 31;
    int gr = rb + r;
    float4 v = make_float4(0.f, 0.f, 0.f, 0.f);
    if (gr < n) v = ((const float4*)X)[gr * 32 + k4];
    *(float4*)&Xs[r][k4 * 4] = v;
  }
  __syncthreads();

  int rg = t >> 4, cg = t & 15;
  int r0 = rg * 4, c0 = cg * 8;
  float acc[4][8];
  #pragma unroll
  for (int i = 0; i < 4; ++i)
    #pragma unroll
    for (int j = 0; j < 8; ++j) acc[i][j] = 0.f;

  for (int k = 0; k < 128; ++k) {
    float4 b0 = *(const float4*)&Ws[k * 128 + c0];
    float4 b1 = *(const float4*)&Ws[k * 128 + c0 + 4];
    #pragma unroll
    for (int i = 0; i < 4; ++i) {
      float a = Xs[r0 + i][k];
      acc[i][0] = fmaf(a, b0.x, acc[i][0]);
      acc[i][1] = fmaf(a, b0.y, acc[i][1]);
      acc[i][2] = fmaf(a, b0.z, acc[i][2]);
      acc[i][3] = fmaf(a, b0.w, acc[i][3]);
      acc[i][4] = fmaf(a, b1.x, acc[i][4]);
      acc[i][5] = fmaf(a, b1.y, acc[i][5]);
      acc[i][6] = fmaf(a, b1.z, acc[i][6]);
      acc[i][7] = fmaf(a, b1.w, acc[i][7]);
    }
  }

  #pragma unroll
  for (int i = 0; i < 4; ++i) {
    int gr = rb + r0 + i;
    if (gr < n) {
      float s = nrm[gr];
      float4 o0 = make_float4(acc[i][0] * s, acc[i][1] * s, acc[i][2] * s, acc[i][3] * s);
      float4 o1 = make_float4(acc[i][4] * s, acc[i][5] * s, acc[i][6] * s, acc[i][7] * s);
      *(float4*)(Y + gr * 128 + c0) = o0;
      *(float4*)(Y + gr * 128 + c0 + 4) = o1;
    }
  }
}

// ---------------- aggregate: Xo = relu(norm[i]*(y_i + sum_{e->i} y_src) + b) ----------------
// one wave per node, float2 per lane (128 channels)

__global__ __launch_bounds__(256) void k_agg(const float* __restrict__ Y,
                                             const int* __restrict__ rowptr, const int* __restrict__ col,
                                             const float* __restrict__ nrm, const float* __restrict__ bias,
                                             float* __restrict__ Xo, int n) {
  int wid = (blockIdx.x * 256 + threadIdx.x) >> 6;
  int lane = threadIdx.x & 63;
  if (wid >= n) return;
  const float2* Yv = (const float2*)Y;
  float2 s = Yv[(size_t)wid * 64 + lane];     // self term
  int e0 = rowptr[wid], e1 = rowptr[wid + 1];
  for (int e = e0; e < e1; ++e) {
    int src = col[e];
    float2 v = Yv[(size_t)src * 64 + lane];
    s.x += v.x;
    s.y += v.y;
  }
  float nm = nrm[wid];
  float2 bb = ((const float2*)bias)[lane];
  float2 o;
  o.x = fmaxf(fmaf(s.x, nm, bb.x), 0.f);
  o.y = fmaxf(fmaf(s.y, nm, bb.y), 0.f);
  ((float2*)Xo)[(size_t)wid * 64 + lane] = o;
}

// ---------------- fused MLP: Out = relu(X@W1+b1)@W2 + b2 ----------------
// block: 32 nodes; H (32x512) staged in LDS

__global__ __launch_bounds__(256) void k_mlp(const float* __restrict__ X,
                                             const float* __restrict__ W1, const float* __restrict__ B1,
                                             const float* __restrict__ W2, const float* __restrict__ B2,
                                             float* __restrict__ Out, int n) {
  __shared__ float Xs[32][132];
  __shared__ float Hs[32][516];
  __shared__ float Wc[128 * 128];
  int t = threadIdx.x;
  int nb = blockIdx.x * 32;

  #pragma unroll
  for (int m = 0; m < 4; ++m) {
    int i4 = m * 256 + t;
    int r = i4 >> 5, k4 = i4 & 31;
    int gr = nb + r;
    float4 v = make_float4(0.f, 0.f, 0.f, 0.f);
    if (gr < n) v = ((const float4*)X)[gr * 32 + k4];
    *(float4*)&Xs[r][k4 * 4] = v;
  }

  // phase 1: H = relu(X@W1 + b1), 4 chunks of 128 ffn cols
  int rg = t >> 5, cg = t & 31;       // 8 x 32
  int r0 = rg * 4, c0 = cg * 4;
  for (int ch = 0; ch < 4; ++ch) {
    __syncthreads();
    #pragma unroll
    for (int m = 0; m < 16; ++m) {
      int i4 = m * 256 + t;
      int k = i4 >> 5, j4 = i4 & 31;
      ((float4*)Wc)[i4] = ((const float4*)(W1 + k * FFN + ch * 128))[j4];
    }
    __syncthreads();
    float acc[4][4] = {{0.f, 0.f, 0.f, 0.f}, {0.f, 0.f, 0.f, 0.f},
                       {0.f, 0.f, 0.f, 0.f}, {0.f, 0.f, 0.f, 0.f}};
    for (int k = 0; k < 128; ++k) {
      float4 b = *(const float4*)&Wc[k * 128 + c0];
      #pragma unroll
      for (int i = 0; i < 4; ++i) {
        float a = Xs[r0 + i][k];
        acc[i][0] = fmaf(a, b.x, acc[i][0]);
        acc[i][1] = fmaf(a, b.y, acc[i][1]);
        acc[i][2] = fmaf(a, b.z, acc[i][2]);
        acc[i][3] = fmaf(a, b.w, acc[i][3]);
      }
    }
    float4 bb = ((const float4*)(B1 + ch * 128))[cg];
    #pragma unroll
    for (int i = 0; i < 4; ++i) {
      float4 h;
      h.x = fmaxf(acc[i][0] + bb.x, 0.f);
      h.y = fmaxf(acc[i][1] + bb.y, 0.f);
      h.z = fmaxf(acc[i][2] + bb.z, 0.f);
      h.w = fmaxf(acc[i][3] + bb.w, 0.f);
      *(float4*)&Hs[r0 + i][ch * 128 + c0] = h;
    }
  }

  // phase 2: Out = H@W2 + b2, k in 4 chunks of 128
  int rg2 = t >> 4, cg2 = t & 15;     // 16 x 16
  int r20 = rg2 * 2;
  float acc2[2][4] = {{0.f, 0.f, 0.f, 0.f}, {0.f, 0.f, 0.f, 0.f}};
  for (int ch = 0; ch < 4; ++ch) {
    __syncthreads();
    #pragma unroll
    for (int m = 0; m < 8; ++m) {
      int i4 = m * 256 + t;
      ((float4*)Wc)[i4] = ((const float4*)(W2 + ch * 128 * BOT))[i4];
    }
    __syncthreads();
    for (int kk = 0; kk < 128; ++kk) {
      float4 b = *(const float4*)&Wc[kk * 64 + cg2 * 4];
      #pragma unroll
      for (int i = 0; i < 2; ++i) {
        float a = Hs[r20 + i][ch * 128 + kk];
        acc2[i][0] = fmaf(a, b.x, acc2[i][0]);
        acc2[i][1] = fmaf(a, b.y, acc2[i][1]);
        acc2[i][2] = fmaf(a, b.z, acc2[i][2]);
        acc2[i][3] = fmaf(a, b.w, acc2[i][3]);
      }
    }
  }
  float4 bb2 = ((const float4*)B2)[cg2];
  #pragma unroll
  for (int i = 0; i < 2; ++i) {
    int gr = nb + r20 + i;
    if (gr < n) {
      float4 o;
      o.x = acc2[i][0] + bb2.x;
      o.y = acc2[i][1] + bb2.y;
      o.z = acc2[i][2] + bb2.z;
      o.w = acc2[i][3] + bb2.w;
      ((float4*)Out)[gr * 16 + cg2] = o;
    }
  }
}

extern "C" void kernel_launch(void* const* d_in, const int* in_sizes, int n_in,
                              void* d_out, int out_size, void* d_ws, size_t ws_size,
                              hipStream_t stream) {
  const float* x     = (const float*)d_in[0];
  const int*   ei    = (const int*)d_in[1];
  const float* convW = (const float*)d_in[2];
  const float* convB = (const float*)d_in[3];
  const float* w1    = (const float*)d_in[4];
  const float* b1    = (const float*)d_in[5];
  const float* w2    = (const float*)d_in[6];
  const float* b2    = (const float*)d_in[7];
  float* out = (float*)d_out;

  int N = in_sizes[0] / D;
  int E = in_sizes[1] / 2;
  int L = in_sizes[2] / (D * D);

  char* ws = (char*)d_ws;
  size_t off = 0;
  auto alloc = [&](size_t bytes) -> char* {
    char* p = ws + off;
    off += (bytes + 255) & ~(size_t)255;
    return p;
  };
  float* nrm   = (float*)alloc((size_t)N * 4);
  int* cnt     = (int*)alloc((size_t)N * 4);
  int* part    = (int*)alloc((size_t)N * 4);
  int* rowptr  = (int*)alloc((size_t)(N + 1) * 4);
  int* cursor  = (int*)alloc((size_t)N * 4);
  int* bsum    = (int*)alloc(256 * 4);
  int* boff    = (int*)alloc(256 * 4);
  int* col     = (int*)alloc((size_t)E * 4);
  float* bufA  = (float*)alloc((size_t)N * D * 4);
  float* bufB  = (float*)alloc((size_t)N * D * 4);

  int gN = (N + 255) / 256;
  int gE = (E + 255) / 256;

  k_zero<<<gN, 256, 0, stream>>>(cnt, N);
  k_hist<<<gE, 256, 0, stream>>>(ei, cnt, E);
  k_norm<<<gN, 256, 0, stream>>>(cnt, nrm, N);
  k_scan1<<<gN, 256, 0, stream>>>(cnt, part, bsum, N);
  k_scan2<<<1, 256, 0, stream>>>(bsum, boff, gN);
  k_scan3<<<gN, 256, 0, stream>>>(part, boff, rowptr, cursor, N, E);
  k_fill<<<gE, 256, 0, stream>>>(ei, cursor, col, E);

  const float* xin = x;
  for (int l = 0; l < L; ++l) {
    k_xw<<<(N + 63) / 64, 256, 0, stream>>>(xin, convW + (size_t)l * D * D, nrm, bufA, N);
    k_agg<<<(N + 3) / 4, 256, 0, stream>>>(bufA, rowptr, col, nrm, convB + (size_t)l * D, bufB, N);
    xin = bufB;
  }

  k_mlp<<<(N + 31) / 32, 256, 0, stream>>>(xin, w1, b1, w2, b2, out, N);
}

// Round 2
// 697.363 us; speedup vs baseline: 1.0678x; 1.0678x over previous
//
#include <hip/hip_runtime.h>

#define D 128
#define FFN 512
#define BOT 64

// ---------------- CSR build ----------------

__global__ __launch_bounds__(256) void k_hist(const int* __restrict__ ei, int* __restrict__ cnt, int nE) {
  int i = blockIdx.x * 256 + threadIdx.x;
  if (i < nE) atomicAdd(&cnt[ei[nE + i]], 1);   // dst = ei[E + i]
}

__global__ __launch_bounds__(256) void k_scan1(const int* __restrict__ cnt, int* __restrict__ part,
                                               int* __restrict__ bsum, int n) {
  __shared__ int s[256];
  int t = threadIdx.x;
  int i = blockIdx.x * 256 + t;
  int v = (i < n) ? cnt[i] : 0;
  s[t] = v;
  __syncthreads();
  for (int d = 1; d < 256; d <<= 1) {
    int add = (t >= d) ? s[t - d] : 0;
    __syncthreads();
    s[t] += add;
    __syncthreads();
  }
  if (i < n) part[i] = s[t] - v;
  if (t == 255) bsum[blockIdx.x] = s[255];
}

__global__ __launch_bounds__(256) void k_scan2(const int* __restrict__ bsum, int* __restrict__ boff, int nb) {
  __shared__ int s[256];
  int t = threadIdx.x;
  int v = (t < nb) ? bsum[t] : 0;
  s[t] = v;
  __syncthreads();
  for (int d = 1; d < 256; d <<= 1) {
    int add = (t >= d) ? s[t - d] : 0;
    __syncthreads();
    s[t] += add;
    __syncthreads();
  }
  boff[t] = s[t] - v;
}

// also computes nrm = rsqrt(deg+1)
__global__ __launch_bounds__(256) void k_scan3(const int* __restrict__ part, const int* __restrict__ boff,
                                               const int* __restrict__ cnt, float* __restrict__ nrm,
                                               int* __restrict__ rowptr, int* __restrict__ cursor,
                                               int n, int nE) {
  int i = blockIdx.x * 256 + threadIdx.x;
  if (i < n) {
    int r = part[i] + boff[i >> 8];
    rowptr[i] = r;
    cursor[i] = r;
    nrm[i] = rsqrtf((float)cnt[i] + 1.0f);
  }
  if (i == 0) rowptr[n] = nE;
}

__global__ __launch_bounds__(256) void k_fill(const int* __restrict__ ei, int* __restrict__ cursor,
                                              int* __restrict__ col, int nE) {
  int i = blockIdx.x * 256 + threadIdx.x;
  if (i < nE) {
    int s = ei[i];
    int d2 = ei[nE + i];
    int pos = atomicAdd(&cursor[d2], 1);
    col[pos] = s;
  }
}

// ---------------- per-layer: Y = (X @ W) * norm[row] ----------------
// block: 64 rows, 256 threads, thread tile 4x8; W read direct from global (L2)

__global__ __launch_bounds__(256, 4) void k_xw(const float* __restrict__ X, const float* __restrict__ W,
                                               const float* __restrict__ nrm, float* __restrict__ Y, int n) {
  __shared__ float Xs[64][132];
  int t = threadIdx.x;
  int rb = blockIdx.x * 64;

  #pragma unroll
  for (int m = 0; m < 8; ++m) {
    int i4 = m * 256 + t;
    int r = i4 >> 5, k4 = i4 & 31;
    int gr = rb + r;
    float4 v = make_float4(0.f, 0.f, 0.f, 0.f);
    if (gr < n) v = ((const float4*)X)[gr * 32 + k4];
    *(float4*)&Xs[r][k4 * 4] = v;
  }
  __syncthreads();

  int rg = t >> 4, cg = t & 15;
  int r0 = rg * 4, c0 = cg * 8;
  const float* Wp = W + c0;

  float acc[4][8];
  #pragma unroll
  for (int i = 0; i < 4; ++i)
    #pragma unroll
    for (int j = 0; j < 8; ++j) acc[i][j] = 0.f;

  for (int k = 0; k < 128; k += 2) {
    float4 b00 = *(const float4*)(Wp + k * 128);
    float4 b01 = *(const float4*)(Wp + k * 128 + 4);
    float4 b10 = *(const float4*)(Wp + k * 128 + 128);
    float4 b11 = *(const float4*)(Wp + k * 128 + 132);
    float2 a0 = *(const float2*)&Xs[r0 + 0][k];
    float2 a1 = *(const float2*)&Xs[r0 + 1][k];
    float2 a2 = *(const float2*)&Xs[r0 + 2][k];
    float2 a3 = *(const float2*)&Xs[r0 + 3][k];
    float ax[4] = {a0.x, a1.x, a2.x, a3.x};
    float ay[4] = {a0.y, a1.y, a2.y, a3.y};
    #pragma unroll
    for (int i = 0; i < 4; ++i) {
      acc[i][0] = fmaf(ax[i], b00.x, acc[i][0]);
      acc[i][1] = fmaf(ax[i], b00.y, acc[i][1]);
      acc[i][2] = fmaf(ax[i], b00.z, acc[i][2]);
      acc[i][3] = fmaf(ax[i], b00.w, acc[i][3]);
      acc[i][4] = fmaf(ax[i], b01.x, acc[i][4]);
      acc[i][5] = fmaf(ax[i], b01.y, acc[i][5]);
      acc[i][6] = fmaf(ax[i], b01.z, acc[i][6]);
      acc[i][7] = fmaf(ax[i], b01.w, acc[i][7]);
    }
    #pragma unroll
    for (int i = 0; i < 4; ++i) {
      acc[i][0] = fmaf(ay[i], b10.x, acc[i][0]);
      acc[i][1] = fmaf(ay[i], b10.y, acc[i][1]);
      acc[i][2] = fmaf(ay[i], b10.z, acc[i][2]);
      acc[i][3] = fmaf(ay[i], b10.w, acc[i][3]);
      acc[i][4] = fmaf(ay[i], b11.x, acc[i][4]);
      acc[i][5] = fmaf(ay[i], b11.y, acc[i][5]);
      acc[i][6] = fmaf(ay[i], b11.z, acc[i][6]);
      acc[i][7] = fmaf(ay[i], b11.w, acc[i][7]);
    }
  }

  #pragma unroll
  for (int i = 0; i < 4; ++i) {
    int gr = rb + r0 + i;
    if (gr < n) {
      float s = nrm[gr];
      float4 o0 = make_float4(acc[i][0] * s, acc[i][1] * s, acc[i][2] * s, acc[i][3] * s);
      float4 o1 = make_float4(acc[i][4] * s, acc[i][5] * s, acc[i][6] * s, acc[i][7] * s);
      *(float4*)(Y + gr * 128 + c0) = o0;
      *(float4*)(Y + gr * 128 + c0 + 4) = o1;
    }
  }
}

// ---------------- aggregate: Xo = relu(norm[i]*(y_i + sum y_src) + b) ----------------

__global__ __launch_bounds__(256) void k_agg(const float* __restrict__ Y,
                                             const int* __restrict__ rowptr, const int* __restrict__ col,
                                             const float* __restrict__ nrm, const float* __restrict__ bias,
                                             float* __restrict__ Xo, int n) {
  int wid = (blockIdx.x * 256 + threadIdx.x) >> 6;
  int lane = threadIdx.x & 63;
  if (wid >= n) return;
  const float2* Yv = (const float2*)Y;
  float2 s0 = Yv[(size_t)wid * 64 + lane];     // self term
  float2 s1 = make_float2(0.f, 0.f);
  float2 s2 = make_float2(0.f, 0.f);
  float2 s3 = make_float2(0.f, 0.f);
  int e0 = rowptr[wid], e1 = rowptr[wid + 1];
  int e = e0;
  for (; e + 4 <= e1; e += 4) {
    int c0 = col[e], c1 = col[e + 1], c2 = col[e + 2], c3 = col[e + 3];
    float2 v0 = Yv[(size_t)c0 * 64 + lane];
    float2 v1 = Yv[(size_t)c1 * 64 + lane];
    float2 v2 = Yv[(size_t)c2 * 64 + lane];
    float2 v3 = Yv[(size_t)c3 * 64 + lane];
    s0.x += v0.x; s0.y += v0.y;
    s1.x += v1.x; s1.y += v1.y;
    s2.x += v2.x; s2.y += v2.y;
    s3.x += v3.x; s3.y += v3.y;
  }
  for (; e < e1; ++e) {
    int c = col[e];
    float2 v = Yv[(size_t)c * 64 + lane];
    s0.x += v.x; s0.y += v.y;
  }
  float2 s;
  s.x = (s0.x + s1.x) + (s2.x + s3.x);
  s.y = (s0.y + s1.y) + (s2.y + s3.y);
  float nm = nrm[wid];
  float2 bb = ((const float2*)bias)[lane];
  float2 o;
  o.x = fmaxf(fmaf(s.x, nm, bb.x), 0.f);
  o.y = fmaxf(fmaf(s.y, nm, bb.y), 0.f);
  ((float2*)Xo)[(size_t)wid * 64 + lane] = o;
}

// ---------------- fused MLP: Out = relu(X@W1+b1)@W2 + b2 ----------------
// block: 32 nodes, 256 threads; per FFN-chunk (128 cols): H-chunk via LDS,
// Out accumulated in registers. LDS = Xs(17K)+Hs(17K) = 34 KB -> 4 blocks/CU.

__global__ __launch_bounds__(256, 4) void k_mlp(const float* __restrict__ X,
                                                const float* __restrict__ W1, const float* __restrict__ B1,
                                                const float* __restrict__ W2, const float* __restrict__ B2,
                                                float* __restrict__ Out, int n) {
  __shared__ float Xs[32][132];
  __shared__ float Hs[32][132];
  int t = threadIdx.x;
  int nb = blockIdx.x * 32;

  #pragma unroll
  for (int m = 0; m < 4; ++m) {
    int i4 = m * 256 + t;
    int r = i4 >> 5, k4 = i4 & 31;
    int gr = nb + r;
    float4 v = make_float4(0.f, 0.f, 0.f, 0.f);
    if (gr < n) v = ((const float4*)X)[gr * 32 + k4];
    *(float4*)&Xs[r][k4 * 4] = v;
  }
  __syncthreads();

  // phase1 tile: 2 rows x 8 cols ; phase2 tile: 2 rows x 4 cols
  int rg = t >> 4, cg = t & 15;
  int r0 = rg * 2, c0 = cg * 8;
  int c20 = cg * 4;

  float acc2[2][4] = {{0.f, 0.f, 0.f, 0.f}, {0.f, 0.f, 0.f, 0.f}};

  for (int ch = 0; ch < 4; ++ch) {
    // ---- phase 1: H-chunk = relu(X @ W1[:, ch*128 .. +128] + b1) ----
    const float* Wp1 = W1 + ch * 128 + c0;
    float acc[2][8];
    #pragma unroll
    for (int i = 0; i < 2; ++i)
      #pragma unroll
      for (int j = 0; j < 8; ++j) acc[i][j] = 0.f;

    for (int k = 0; k < 128; k += 2) {
      float4 b00 = *(const float4*)(Wp1 + (size_t)k * FFN);
      float4 b01 = *(const float4*)(Wp1 + (size_t)k * FFN + 4);
      float4 b10 = *(const float4*)(Wp1 + (size_t)(k + 1) * FFN);
      float4 b11 = *(const float4*)(Wp1 + (size_t)(k + 1) * FFN + 4);
      float2 a0 = *(const float2*)&Xs[r0 + 0][k];
      float2 a1 = *(const float2*)&Xs[r0 + 1][k];
      float ax[2] = {a0.x, a1.x};
      float ay[2] = {a0.y, a1.y};
      #pragma unroll
      for (int i = 0; i < 2; ++i) {
        acc[i][0] = fmaf(ax[i], b00.x, acc[i][0]);
        acc[i][1] = fmaf(ax[i], b00.y, acc[i][1]);
        acc[i][2] = fmaf(ax[i], b00.z, acc[i][2]);
        acc[i][3] = fmaf(ax[i], b00.w, acc[i][3]);
        acc[i][4] = fmaf(ax[i], b01.x, acc[i][4]);
        acc[i][5] = fmaf(ax[i], b01.y, acc[i][5]);
        acc[i][6] = fmaf(ax[i], b01.z, acc[i][6]);
        acc[i][7] = fmaf(ax[i], b01.w, acc[i][7]);
        acc[i][0] = fmaf(ay[i], b10.x, acc[i][0]);
        acc[i][1] = fmaf(ay[i], b10.y, acc[i][1]);
        acc[i][2] = fmaf(ay[i], b10.z, acc[i][2]);
        acc[i][3] = fmaf(ay[i], b10.w, acc[i][3]);
        acc[i][4] = fmaf(ay[i], b11.x, acc[i][4]);
        acc[i][5] = fmaf(ay[i], b11.y, acc[i][5]);
        acc[i][6] = fmaf(ay[i], b11.z, acc[i][6]);
        acc[i][7] = fmaf(ay[i], b11.w, acc[i][7]);
      }
    }

    __syncthreads();   // previous phase2 done reading Hs
    {
      const float* bp = B1 + ch * 128 + c0;
      #pragma unroll
      for (int i = 0; i < 2; ++i) {
        float4 h0, h1;
        h0.x = fmaxf(acc[i][0] + bp[0], 0.f);
        h0.y = fmaxf(acc[i][1] + bp[1], 0.f);
        h0.z = fmaxf(acc[i][2] + bp[2], 0.f);
        h0.w = fmaxf(acc[i][3] + bp[3], 0.f);
        h1.x = fmaxf(acc[i][4] + bp[4], 0.f);
        h1.y = fmaxf(acc[i][5] + bp[5], 0.f);
        h1.z = fmaxf(acc[i][6] + bp[6], 0.f);
        h1.w = fmaxf(acc[i][7] + bp[7], 0.f);
        *(float4*)&Hs[r0 + i][c0] = h0;
        *(float4*)&Hs[r0 + i][c0 + 4] = h1;
      }
    }
    __syncthreads();   // Hs chunk ready

    // ---- phase 2: Out += relu-chunk @ W2[ch*128 .. , :] ----
    const float* Wp2 = W2 + (size_t)(ch * 128) * BOT + c20;
    for (int k = 0; k < 128; k += 4) {
      float4 b0 = *(const float4*)(Wp2 + (size_t)(k + 0) * BOT);
      float4 b1 = *(const float4*)(Wp2 + (size_t)(k + 1) * BOT);
      float4 b2 = *(const float4*)(Wp2 + (size_t)(k + 2) * BOT);
      float4 b3 = *(const float4*)(Wp2 + (size_t)(k + 3) * BOT);
      float4 a0 = *(const float4*)&Hs[r0 + 0][k];
      float4 a1 = *(const float4*)&Hs[r0 + 1][k];
      float aks[2][4] = {{a0.x, a0.y, a0.z, a0.w}, {a1.x, a1.y, a1.z, a1.w}};
      #pragma unroll
      for (int i = 0; i < 2; ++i) {
        acc2[i][0] = fmaf(aks[i][0], b0.x, acc2[i][0]);
        acc2[i][1] = fmaf(aks[i][0], b0.y, acc2[i][1]);
        acc2[i][2] = fmaf(aks[i][0], b0.z, acc2[i][2]);
        acc2[i][3] = fmaf(aks[i][0], b0.w, acc2[i][3]);
        acc2[i][0] = fmaf(aks[i][1], b1.x, acc2[i][0]);
        acc2[i][1] = fmaf(aks[i][1], b1.y, acc2[i][1]);
        acc2[i][2] = fmaf(aks[i][1], b1.z, acc2[i][2]);
        acc2[i][3] = fmaf(aks[i][1], b1.w, acc2[i][3]);
        acc2[i][0] = fmaf(aks[i][2], b2.x, acc2[i][0]);
        acc2[i][1] = fmaf(aks[i][2], b2.y, acc2[i][1]);
        acc2[i][2] = fmaf(aks[i][2], b2.z, acc2[i][2]);
        acc2[i][3] = fmaf(aks[i][2], b2.w, acc2[i][3]);
        acc2[i][0] = fmaf(aks[i][3], b3.x, acc2[i][0]);
        acc2[i][1] = fmaf(aks[i][3], b3.y, acc2[i][1]);
        acc2[i][2] = fmaf(aks[i][3], b3.z, acc2[i][2]);
        acc2[i][3] = fmaf(aks[i][3], b3.w, acc2[i][3]);
      }
    }
  }

  float4 bb2 = ((const float4*)B2)[cg];
  #pragma unroll
  for (int i = 0; i < 2; ++i) {
    int gr = nb + r0 + i;
    if (gr < n) {
      float4 o;
      o.x = acc2[i][0] + bb2.x;
      o.y = acc2[i][1] + bb2.y;
      o.z = acc2[i][2] + bb2.z;
      o.w = acc2[i][3] + bb2.w;
      ((float4*)Out)[(size_t)gr * 16 + cg] = o;
    }
  }
}

extern "C" void kernel_launch(void* const* d_in, const int* in_sizes, int n_in,
                              void* d_out, int out_size, void* d_ws, size_t ws_size,
                              hipStream_t stream) {
  const float* x     = (const float*)d_in[0];
  const int*   ei    = (const int*)d_in[1];
  const float* convW = (const float*)d_in[2];
  const float* convB = (const float*)d_in[3];
  const float* w1    = (const float*)d_in[4];
  const float* b1    = (const float*)d_in[5];
  const float* w2    = (const float*)d_in[6];
  const float* b2    = (const float*)d_in[7];
  float* out = (float*)d_out;

  int N = in_sizes[0] / D;
  int E = in_sizes[1] / 2;
  int L = in_sizes[2] / (D * D);

  char* ws = (char*)d_ws;
  size_t off = 0;
  auto alloc = [&](size_t bytes) -> char* {
    char* p = ws + off;
    off += (bytes + 255) & ~(size_t)255;
    return p;
  };
  float* nrm   = (float*)alloc((size_t)N * 4);
  int* cnt     = (int*)alloc((size_t)N * 4);
  int* part    = (int*)alloc((size_t)N * 4);
  int* rowptr  = (int*)alloc((size_t)(N + 1) * 4);
  int* cursor  = (int*)alloc((size_t)N * 4);
  int* bsum    = (int*)alloc(256 * 4);
  int* boff    = (int*)alloc(256 * 4);
  int* col     = (int*)alloc((size_t)E * 4);
  float* bufA  = (float*)alloc((size_t)N * D * 4);
  float* bufB  = (float*)alloc((size_t)N * D * 4);

  int gN = (N + 255) / 256;
  int gE = (E + 255) / 256;

  hipMemsetAsync(cnt, 0, (size_t)N * 4, stream);
  k_hist<<<gE, 256, 0, stream>>>(ei, cnt, E);
  k_scan1<<<gN, 256, 0, stream>>>(cnt, part, bsum, N);
  k_scan2<<<1, 256, 0, stream>>>(bsum, boff, gN);
  k_scan3<<<gN, 256, 0, stream>>>(part, boff, cnt, nrm, rowptr, cursor, N, E);
  k_fill<<<gE, 256, 0, stream>>>(ei, cursor, col, E);

  const float* xin = x;
  for (int l = 0; l < L; ++l) {
    k_xw<<<(N + 63) / 64, 256, 0, stream>>>(xin, convW + (size_t)l * D * D, nrm, bufA, N);
    k_agg<<<(N + 3) / 4, 256, 0, stream>>>(bufA, rowptr, col, nrm, convB + (size_t)l * D, bufB, N);
    xin = bufB;
  }

  k_mlp<<<(N + 31) / 32, 256, 0, stream>>>(xin, w1, b1, w2, b2, out, N);
}

// Round 3
// 563.846 us; speedup vs baseline: 1.3206x; 1.2368x over previous
//
#include <hip/hip_runtime.h>

#define D 128
#define FFN 512
#define BOT 64

// ---------------- CSR build ----------------

__global__ __launch_bounds__(256) void k_hist(const int* __restrict__ ei, int* __restrict__ cnt, int nE) {
  int i = blockIdx.x * 256 + threadIdx.x;
  if (i < nE) atomicAdd(&cnt[ei[nE + i]], 1);   // dst = ei[E + i]
}

__global__ __launch_bounds__(256) void k_scan1(const int* __restrict__ cnt, int* __restrict__ part,
                                               int* __restrict__ bsum, int n) {
  __shared__ int s[256];
  int t = threadIdx.x;
  int i = blockIdx.x * 256 + t;
  int v = (i < n) ? cnt[i] : 0;
  s[t] = v;
  __syncthreads();
  for (int d = 1; d < 256; d <<= 1) {
    int add = (t >= d) ? s[t - d] : 0;
    __syncthreads();
    s[t] += add;
    __syncthreads();
  }
  if (i < n) part[i] = s[t] - v;
  if (t == 255) bsum[blockIdx.x] = s[255];
}

__global__ __launch_bounds__(256) void k_scan2(const int* __restrict__ bsum, int* __restrict__ boff, int nb) {
  __shared__ int s[256];
  int t = threadIdx.x;
  int v = (t < nb) ? bsum[t] : 0;
  s[t] = v;
  __syncthreads();
  for (int d = 1; d < 256; d <<= 1) {
    int add = (t >= d) ? s[t - d] : 0;
    __syncthreads();
    s[t] += add;
    __syncthreads();
  }
  boff[t] = s[t] - v;
}

// also computes nrm = rsqrt(deg+1)
__global__ __launch_bounds__(256) void k_scan3(const int* __restrict__ part, const int* __restrict__ boff,
                                               const int* __restrict__ cnt, float* __restrict__ nrm,
                                               int* __restrict__ rowptr, int* __restrict__ cursor,
                                               int n, int nE) {
  int i = blockIdx.x * 256 + threadIdx.x;
  if (i < n) {
    int r = part[i] + boff[i >> 8];
    rowptr[i] = r;
    cursor[i] = r;
    nrm[i] = rsqrtf((float)cnt[i] + 1.0f);
  }
  if (i == 0) rowptr[n] = nE;
}

__global__ __launch_bounds__(256) void k_fill(const int* __restrict__ ei, int* __restrict__ cursor,
                                              int* __restrict__ col, int nE) {
  int i = blockIdx.x * 256 + threadIdx.x;
  if (i < nE) {
    int s = ei[i];
    int d2 = ei[nE + i];
    int pos = atomicAdd(&cursor[d2], 1);
    col[pos] = s;
  }
}

// ---------------- generic fp32 tile GEMM ----------------
// C[M x ?] = A[M x K] @ B[K x ldb] (64-col panel per block), both staged in LDS.
// block: 64 rows x 64 cols, 256 threads, 4x4 thread tile.
// LDS = 33.8 KB (As) + 32 KB (Bs) = 66 KB -> 2 blocks/CU.
// MODE 0: C = acc * aux[row]   (conv: Y = XW * nrm)
// MODE 1: C = relu(acc + aux[col])   (fc1)
// MODE 2: C = acc + aux[col]         (fc2)

template<int MODE>
__global__ __launch_bounds__(256, 2) void k_gemm64(const float* __restrict__ A,
                                                   const float* __restrict__ B,
                                                   const float* __restrict__ aux,
                                                   float* __restrict__ C,
                                                   int M, int K, int ldb, int ldc, int nRB) {
  __shared__ float As[64][132];
  __shared__ float Bs[128][64];
  int t = threadIdx.x;
  int rb = blockIdx.x % nRB;
  int cb = blockIdx.x / nRB;
  int rbase = rb * 64;
  int cbase = cb * 64;

  int rg = t >> 4, cg = t & 15;
  int r0 = rg * 4, c0 = cg * 4;

  float acc[4][4] = {{0.f,0.f,0.f,0.f},{0.f,0.f,0.f,0.f},{0.f,0.f,0.f,0.f},{0.f,0.f,0.f,0.f}};

  for (int kc = 0; kc < K; kc += 128) {
    __syncthreads();   // previous compute done reading LDS
    // stage A: 64 x 128
    #pragma unroll
    for (int m = 0; m < 8; ++m) {
      int idx = m * 256 + t;
      int r = idx >> 5, k4 = idx & 31;
      int gr = rbase + r;
      float4 v = make_float4(0.f, 0.f, 0.f, 0.f);
      if (gr < M) v = *(const float4*)(A + (size_t)gr * K + kc + k4 * 4);
      *(float4*)&As[r][k4 * 4] = v;
    }
    // stage B panel: 128 x 64
    #pragma unroll
    for (int m = 0; m < 8; ++m) {
      int idx = m * 256 + t;
      int k = idx >> 4, c4 = idx & 15;
      float4 v = *(const float4*)(B + (size_t)(kc + k) * ldb + cbase + c4 * 4);
      *(float4*)&Bs[k][c4 * 4] = v;
    }
    __syncthreads();

    #pragma unroll 4
    for (int k = 0; k < 128; k += 4) {
      float4 a0 = *(const float4*)&As[r0 + 0][k];
      float4 a1 = *(const float4*)&As[r0 + 1][k];
      float4 a2 = *(const float4*)&As[r0 + 2][k];
      float4 a3 = *(const float4*)&As[r0 + 3][k];
      float4 b0 = *(const float4*)&Bs[k + 0][c0];
      float4 b1 = *(const float4*)&Bs[k + 1][c0];
      float4 b2 = *(const float4*)&Bs[k + 2][c0];
      float4 b3 = *(const float4*)&Bs[k + 3][c0];
      float ar[4][4] = {{a0.x, a0.y, a0.z, a0.w},
                        {a1.x, a1.y, a1.z, a1.w},
                        {a2.x, a2.y, a2.z, a2.w},
                        {a3.x, a3.y, a3.z, a3.w}};
      #pragma unroll
      for (int i = 0; i < 4; ++i) {
        acc[i][0] = fmaf(ar[i][0], b0.x, acc[i][0]);
        acc[i][1] = fmaf(ar[i][0], b0.y, acc[i][1]);
        acc[i][2] = fmaf(ar[i][0], b0.z, acc[i][2]);
        acc[i][3] = fmaf(ar[i][0], b0.w, acc[i][3]);
        acc[i][0] = fmaf(ar[i][1], b1.x, acc[i][0]);
        acc[i][1] = fmaf(ar[i][1], b1.y, acc[i][1]);
        acc[i][2] = fmaf(ar[i][1], b1.z, acc[i][2]);
        acc[i][3] = fmaf(ar[i][1], b1.w, acc[i][3]);
        acc[i][0] = fmaf(ar[i][2], b2.x, acc[i][0]);
        acc[i][1] = fmaf(ar[i][2], b2.y, acc[i][1]);
        acc[i][2] = fmaf(ar[i][2], b2.z, acc[i][2]);
        acc[i][3] = fmaf(ar[i][2], b2.w, acc[i][3]);
        acc[i][0] = fmaf(ar[i][3], b3.x, acc[i][0]);
        acc[i][1] = fmaf(ar[i][3], b3.y, acc[i][1]);
        acc[i][2] = fmaf(ar[i][3], b3.z, acc[i][2]);
        acc[i][3] = fmaf(ar[i][3], b3.w, acc[i][3]);
      }
    }
  }

  if (MODE == 0) {
    #pragma unroll
    for (int i = 0; i < 4; ++i) {
      int gr = rbase + r0 + i;
      if (gr < M) {
        float s = aux[gr];
        float4 o = make_float4(acc[i][0] * s, acc[i][1] * s, acc[i][2] * s, acc[i][3] * s);
        *(float4*)(C + (size_t)gr * ldc + cbase + c0) = o;
      }
    }
  } else {
    float4 bb = *(const float4*)(aux + cbase + c0);
    #pragma unroll
    for (int i = 0; i < 4; ++i) {
      int gr = rbase + r0 + i;
      if (gr < M) {
        float4 o;
        o.x = acc[i][0] + bb.x;
        o.y = acc[i][1] + bb.y;
        o.z = acc[i][2] + bb.z;
        o.w = acc[i][3] + bb.w;
        if (MODE == 1) {
          o.x = fmaxf(o.x, 0.f); o.y = fmaxf(o.y, 0.f);
          o.z = fmaxf(o.z, 0.f); o.w = fmaxf(o.w, 0.f);
        }
        *(float4*)(C + (size_t)gr * ldc + cbase + c0) = o;
      }
    }
  }
}

// ---------------- aggregate: Xo = relu(norm[i]*(y_i + sum y_src) + b) ----------------

__global__ __launch_bounds__(256) void k_agg(const float* __restrict__ Y,
                                             const int* __restrict__ rowptr, const int* __restrict__ col,
                                             const float* __restrict__ nrm, const float* __restrict__ bias,
                                             float* __restrict__ Xo, int n) {
  int wid = (blockIdx.x * 256 + threadIdx.x) >> 6;
  int lane = threadIdx.x & 63;
  if (wid >= n) return;
  const float2* Yv = (const float2*)Y;
  float2 s0 = Yv[(size_t)wid * 64 + lane];     // self term
  float2 s1 = make_float2(0.f, 0.f);
  float2 s2 = make_float2(0.f, 0.f);
  float2 s3 = make_float2(0.f, 0.f);
  int e0 = rowptr[wid], e1 = rowptr[wid + 1];
  int e = e0;
  for (; e + 4 <= e1; e += 4) {
    int c0 = col[e], c1 = col[e + 1], c2 = col[e + 2], c3 = col[e + 3];
    float2 v0 = Yv[(size_t)c0 * 64 + lane];
    float2 v1 = Yv[(size_t)c1 * 64 + lane];
    float2 v2 = Yv[(size_t)c2 * 64 + lane];
    float2 v3 = Yv[(size_t)c3 * 64 + lane];
    s0.x += v0.x; s0.y += v0.y;
    s1.x += v1.x; s1.y += v1.y;
    s2.x += v2.x; s2.y += v2.y;
    s3.x += v3.x; s3.y += v3.y;
  }
  for (; e < e1; ++e) {
    int c = col[e];
    float2 v = Yv[(size_t)c * 64 + lane];
    s0.x += v.x; s0.y += v.y;
  }
  float2 s;
  s.x = (s0.x + s1.x) + (s2.x + s3.x);
  s.y = (s0.y + s1.y) + (s2.y + s3.y);
  float nm = nrm[wid];
  float2 bb = ((const float2*)bias)[lane];
  float2 o;
  o.x = fmaxf(fmaf(s.x, nm, bb.x), 0.f);
  o.y = fmaxf(fmaf(s.y, nm, bb.y), 0.f);
  ((float2*)Xo)[(size_t)wid * 64 + lane] = o;
}

extern "C" void kernel_launch(void* const* d_in, const int* in_sizes, int n_in,
                              void* d_out, int out_size, void* d_ws, size_t ws_size,
                              hipStream_t stream) {
  const float* x     = (const float*)d_in[0];
  const int*   ei    = (const int*)d_in[1];
  const float* convW = (const float*)d_in[2];
  const float* convB = (const float*)d_in[3];
  const float* w1    = (const float*)d_in[4];
  const float* b1    = (const float*)d_in[5];
  const float* w2    = (const float*)d_in[6];
  const float* b2    = (const float*)d_in[7];
  float* out = (float*)d_out;

  int N = in_sizes[0] / D;
  int E = in_sizes[1] / 2;
  int L = in_sizes[2] / (D * D);

  char* ws = (char*)d_ws;
  size_t off = 0;
  auto alloc = [&](size_t bytes) -> char* {
    char* p = ws + off;
    off += (bytes + 255) & ~(size_t)255;
    return p;
  };
  float* nrm   = (float*)alloc((size_t)N * 4);
  int* cnt     = (int*)alloc((size_t)N * 4);
  int* part    = (int*)alloc((size_t)N * 4);
  int* rowptr  = (int*)alloc((size_t)(N + 1) * 4);
  int* cursor  = (int*)alloc((size_t)N * 4);
  int* bsum    = (int*)alloc(256 * 4);
  int* boff    = (int*)alloc(256 * 4);
  int* col     = (int*)alloc((size_t)E * 4);
  float* bufA  = (float*)alloc((size_t)N * D * 4);
  float* bufB  = (float*)alloc((size_t)N * D * 4);

  int gN = (N + 255) / 256;
  int gE = (E + 255) / 256;

  hipMemsetAsync(cnt, 0, (size_t)N * 4, stream);
  k_hist<<<gE, 256, 0, stream>>>(ei, cnt, E);
  k_scan1<<<gN, 256, 0, stream>>>(cnt, part, bsum, N);
  k_scan2<<<1, 256, 0, stream>>>(bsum, boff, gN);
  k_scan3<<<gN, 256, 0, stream>>>(part, boff, cnt, nrm, rowptr, cursor, N, E);
  k_fill<<<gE, 256, 0, stream>>>(ei, cursor, col, E);

  int nRBf = (N + 63) / 64;
  const float* xin = x;
  for (int l = 0; l < L; ++l) {
    // Y = (X @ Wl) * nrm[row]
    k_gemm64<0><<<nRBf * (D / 64), 256, 0, stream>>>(
        xin, convW + (size_t)l * D * D, nrm, bufA, N, D, D, D, nRBf);
    k_agg<<<(N + 3) / 4, 256, 0, stream>>>(bufA, rowptr, col, nrm, convB + (size_t)l * D, bufB, N);
    xin = bufB;
  }

  // ---- MLP: H = relu(X@W1+b1); Out = H@W2+b2 ; H strip-buffered in ws ----
  size_t avail = (ws_size > off) ? (ws_size - off) : 0;
  long long maxRows = (long long)(avail / ((size_t)FFN * 4));
  int Nceil = (N + 63) & ~63;
  long long stripLL = maxRows & ~63LL;
  if (stripLL > Nceil) stripLL = Nceil;
  if (stripLL < 64) stripLL = 64;           // minimal strip; ws assumed to cover this
  int strip = (int)stripLL;
  float* Hbuf = (float*)alloc((size_t)strip * FFN * 4);

  for (int r0 = 0; r0 < N; r0 += strip) {
    int M = N - r0;
    if (M > strip) M = strip;
    int nRB = (M + 63) / 64;
    k_gemm64<1><<<nRB * (FFN / 64), 256, 0, stream>>>(
        xin + (size_t)r0 * D, w1, b1, Hbuf, M, D, FFN, FFN, nRB);
    k_gemm64<2><<<nRB * (BOT / 64), 256, 0, stream>>>(
        Hbuf, w2, b2, out + (size_t)r0 * BOT, M, FFN, BOT, BOT, nRB);
  }
}

// Round 4
// 557.864 us; speedup vs baseline: 1.3348x; 1.0107x over previous
//
#include <hip/hip_runtime.h>

#define D 128
#define FFN 512
#define BOT 64

// ---------------- CSR build ----------------

__global__ __launch_bounds__(256) void k_hist(const int* __restrict__ ei, int* __restrict__ cnt, int nE) {
  int i = blockIdx.x * 256 + threadIdx.x;
  if (i < nE) atomicAdd(&cnt[ei[nE + i]], 1);   // dst = ei[E + i]
}

__global__ __launch_bounds__(256) void k_scan1(const int* __restrict__ cnt, int* __restrict__ part,
                                               int* __restrict__ bsum, int n) {
  __shared__ int s[256];
  int t = threadIdx.x;
  int i = blockIdx.x * 256 + t;
  int v = (i < n) ? cnt[i] : 0;
  s[t] = v;
  __syncthreads();
  for (int d = 1; d < 256; d <<= 1) {
    int add = (t >= d) ? s[t - d] : 0;
    __syncthreads();
    s[t] += add;
    __syncthreads();
  }
  if (i < n) part[i] = s[t] - v;
  if (t == 255) bsum[blockIdx.x] = s[255];
}

__global__ __launch_bounds__(256) void k_scan2(const int* __restrict__ bsum, int* __restrict__ boff, int nb) {
  __shared__ int s[256];
  int t = threadIdx.x;
  int v = (t < nb) ? bsum[t] : 0;
  s[t] = v;
  __syncthreads();
  for (int d = 1; d < 256; d <<= 1) {
    int add = (t >= d) ? s[t - d] : 0;
    __syncthreads();
    s[t] += add;
    __syncthreads();
  }
  boff[t] = s[t] - v;
}

// also computes nrm = rsqrt(deg+1)
__global__ __launch_bounds__(256) void k_scan3(const int* __restrict__ part, const int* __restrict__ boff,
                                               const int* __restrict__ cnt, float* __restrict__ nrm,
                                               int* __restrict__ rowptr, int* __restrict__ cursor,
                                               int n, int nE) {
  int i = blockIdx.x * 256 + threadIdx.x;
  if (i < n) {
    int r = part[i] + boff[i >> 8];
    rowptr[i] = r;
    cursor[i] = r;
    nrm[i] = rsqrtf((float)cnt[i] + 1.0f);
  }
  if (i == 0) rowptr[n] = nE;
}

__global__ __launch_bounds__(256) void k_fill(const int* __restrict__ ei, int* __restrict__ cursor,
                                              int* __restrict__ col, int nE) {
  int i = blockIdx.x * 256 + threadIdx.x;
  if (i < nE) {
    int s = ei[i];
    int d2 = ei[nE + i];
    int pos = atomicAdd(&cursor[d2], 1);
    col[pos] = s;
  }
}

// ---------------- generic fp32 tile GEMM (convs) ----------------
// MODE 0: C = acc * aux[row]

template<int MODE>
__global__ __launch_bounds__(256, 2) void k_gemm64(const float* __restrict__ A,
                                                   const float* __restrict__ B,
                                                   const float* __restrict__ aux,
                                                   float* __restrict__ C,
                                                   int M, int K, int ldb, int ldc, int nRB) {
  __shared__ float As[64][132];
  __shared__ float Bs[128][64];
  int t = threadIdx.x;
  int rb = blockIdx.x % nRB;
  int cb = blockIdx.x / nRB;
  int rbase = rb * 64;
  int cbase = cb * 64;

  int rg = t >> 4, cg = t & 15;
  int r0 = rg * 4, c0 = cg * 4;

  float acc[4][4] = {{0.f,0.f,0.f,0.f},{0.f,0.f,0.f,0.f},{0.f,0.f,0.f,0.f},{0.f,0.f,0.f,0.f}};

  for (int kc = 0; kc < K; kc += 128) {
    __syncthreads();
    #pragma unroll
    for (int m = 0; m < 8; ++m) {
      int idx = m * 256 + t;
      int r = idx >> 5, k4 = idx & 31;
      int gr = rbase + r;
      float4 v = make_float4(0.f, 0.f, 0.f, 0.f);
      if (gr < M) v = *(const float4*)(A + (size_t)gr * K + kc + k4 * 4);
      *(float4*)&As[r][k4 * 4] = v;
    }
    #pragma unroll
    for (int m = 0; m < 8; ++m) {
      int idx = m * 256 + t;
      int k = idx >> 4, c4 = idx & 15;
      float4 v = *(const float4*)(B + (size_t)(kc + k) * ldb + cbase + c4 * 4);
      *(float4*)&Bs[k][c4 * 4] = v;
    }
    __syncthreads();

    #pragma unroll 4
    for (int k = 0; k < 128; k += 4) {
      float4 a0 = *(const float4*)&As[r0 + 0][k];
      float4 a1 = *(const float4*)&As[r0 + 1][k];
      float4 a2 = *(const float4*)&As[r0 + 2][k];
      float4 a3 = *(const float4*)&As[r0 + 3][k];
      float4 b0 = *(const float4*)&Bs[k + 0][c0];
      float4 b1 = *(const float4*)&Bs[k + 1][c0];
      float4 b2 = *(const float4*)&Bs[k + 2][c0];
      float4 b3 = *(const float4*)&Bs[k + 3][c0];
      float ar[4][4] = {{a0.x, a0.y, a0.z, a0.w},
                        {a1.x, a1.y, a1.z, a1.w},
                        {a2.x, a2.y, a2.z, a2.w},
                        {a3.x, a3.y, a3.z, a3.w}};
      #pragma unroll
      for (int i = 0; i < 4; ++i) {
        acc[i][0] = fmaf(ar[i][0], b0.x, acc[i][0]);
        acc[i][1] = fmaf(ar[i][0], b0.y, acc[i][1]);
        acc[i][2] = fmaf(ar[i][0], b0.z, acc[i][2]);
        acc[i][3] = fmaf(ar[i][0], b0.w, acc[i][3]);
        acc[i][0] = fmaf(ar[i][1], b1.x, acc[i][0]);
        acc[i][1] = fmaf(ar[i][1], b1.y, acc[i][1]);
        acc[i][2] = fmaf(ar[i][1], b1.z, acc[i][2]);
        acc[i][3] = fmaf(ar[i][1], b1.w, acc[i][3]);
        acc[i][0] = fmaf(ar[i][2], b2.x, acc[i][0]);
        acc[i][1] = fmaf(ar[i][2], b2.y, acc[i][1]);
        acc[i][2] = fmaf(ar[i][2], b2.z, acc[i][2]);
        acc[i][3] = fmaf(ar[i][2], b2.w, acc[i][3]);
        acc[i][0] = fmaf(ar[i][3], b3.x, acc[i][0]);
        acc[i][1] = fmaf(ar[i][3], b3.y, acc[i][1]);
        acc[i][2] = fmaf(ar[i][3], b3.z, acc[i][2]);
        acc[i][3] = fmaf(ar[i][3], b3.w, acc[i][3]);
      }
    }
  }

  #pragma unroll
  for (int i = 0; i < 4; ++i) {
    int gr = rbase + r0 + i;
    if (gr < M) {
      float s = aux[gr];
      float4 o = make_float4(acc[i][0] * s, acc[i][1] * s, acc[i][2] * s, acc[i][3] * s);
      *(float4*)(C + (size_t)gr * ldc + cbase + c0) = o;
    }
  }
}

// ---------------- fused MLP: Out = relu(X@W1+b1)@W2 + b2 ----------------
// block = 64 rows, 256 threads, 4x4 tiles. 8 FFN chunks of 64; per chunk:
// H-chunk in regs (W1 staged in Bs 64x64, two k-halves) -> relu+b1 -> Hs ->
// W2 chunk staged in Bs -> Out accumulated in regs.
// LDS = Xs 33.8K + Bs 16K + Hs 17.4K = 67.2 KB -> 2 blocks/CU.

__global__ __launch_bounds__(256, 2) void k_mlp2(const float* __restrict__ X,
                                                 const float* __restrict__ W1, const float* __restrict__ B1,
                                                 const float* __restrict__ W2, const float* __restrict__ B2,
                                                 float* __restrict__ Out, int M) {
  __shared__ float Xs[64][132];
  __shared__ float Bs[64][64];
  __shared__ float Hs[64][68];
  int t = threadIdx.x;
  int rbase = blockIdx.x * 64;

  int rg = t >> 4, cg = t & 15;
  int r0 = rg * 4, c0 = cg * 4;

  // stage X rows once
  #pragma unroll
  for (int m = 0; m < 8; ++m) {
    int idx = m * 256 + t;
    int r = idx >> 5, k4 = idx & 31;
    int gr = rbase + r;
    float4 v = make_float4(0.f, 0.f, 0.f, 0.f);
    if (gr < M) v = *(const float4*)(X + (size_t)gr * D + k4 * 4);
    *(float4*)&Xs[r][k4 * 4] = v;
  }

  float acc2[4][4] = {{0.f,0.f,0.f,0.f},{0.f,0.f,0.f,0.f},{0.f,0.f,0.f,0.f},{0.f,0.f,0.f,0.f}};

  for (int ch = 0; ch < FFN / 64; ++ch) {
    float accH[4][4] = {{0.f,0.f,0.f,0.f},{0.f,0.f,0.f,0.f},{0.f,0.f,0.f,0.f},{0.f,0.f,0.f,0.f}};

    // ---- phase 1: H = relu(X @ W1[:, ch*64..+64] + b1), K=128 in two halves ----
    #pragma unroll
    for (int kh = 0; kh < 2; ++kh) {
      __syncthreads();   // done reading Bs (prev phase) / Hs safe
      // stage W1 panel: 64 k-rows x 64 cols
      #pragma unroll
      for (int m = 0; m < 4; ++m) {
        int idx = m * 256 + t;
        int k = idx >> 4, c4 = idx & 15;
        float4 v = *(const float4*)(W1 + (size_t)(kh * 64 + k) * FFN + ch * 64 + c4 * 4);
        *(float4*)&Bs[k][c4 * 4] = v;
      }
      __syncthreads();

      #pragma unroll 4
      for (int k = 0; k < 64; k += 4) {
        float4 a0 = *(const float4*)&Xs[r0 + 0][kh * 64 + k];
        float4 a1 = *(const float4*)&Xs[r0 + 1][kh * 64 + k];
        float4 a2 = *(const float4*)&Xs[r0 + 2][kh * 64 + k];
        float4 a3 = *(const float4*)&Xs[r0 + 3][kh * 64 + k];
        float4 b0 = *(const float4*)&Bs[k + 0][c0];
        float4 b1 = *(const float4*)&Bs[k + 1][c0];
        float4 b2 = *(const float4*)&Bs[k + 2][c0];
        float4 b3 = *(const float4*)&Bs[k + 3][c0];
        float ar[4][4] = {{a0.x, a0.y, a0.z, a0.w},
                          {a1.x, a1.y, a1.z, a1.w},
                          {a2.x, a2.y, a2.z, a2.w},
                          {a3.x, a3.y, a3.z, a3.w}};
        #pragma unroll
        for (int i = 0; i < 4; ++i) {
          accH[i][0] = fmaf(ar[i][0], b0.x, accH[i][0]);
          accH[i][1] = fmaf(ar[i][0], b0.y, accH[i][1]);
          accH[i][2] = fmaf(ar[i][0], b0.z, accH[i][2]);
          accH[i][3] = fmaf(ar[i][0], b0.w, accH[i][3]);
          accH[i][0] = fmaf(ar[i][1], b1.x, accH[i][0]);
          accH[i][1] = fmaf(ar[i][1], b1.y, accH[i][1]);
          accH[i][2] = fmaf(ar[i][1], b1.z, accH[i][2]);
          accH[i][3] = fmaf(ar[i][1], b1.w, accH[i][3]);
          accH[i][0] = fmaf(ar[i][2], b2.x, accH[i][0]);
          accH[i][1] = fmaf(ar[i][2], b2.y, accH[i][1]);
          accH[i][2] = fmaf(ar[i][2], b2.z, accH[i][2]);
          accH[i][3] = fmaf(ar[i][2], b2.w, accH[i][3]);
          accH[i][0] = fmaf(ar[i][3], b3.x, accH[i][0]);
          accH[i][1] = fmaf(ar[i][3], b3.y, accH[i][1]);
          accH[i][2] = fmaf(ar[i][3], b3.z, accH[i][2]);
          accH[i][3] = fmaf(ar[i][3], b3.w, accH[i][3]);
        }
      }
    }

    // relu + bias -> Hs
    {
      float4 bb = *(const float4*)(B1 + ch * 64 + c0);
      #pragma unroll
      for (int i = 0; i < 4; ++i) {
        float4 h;
        h.x = fmaxf(accH[i][0] + bb.x, 0.f);
        h.y = fmaxf(accH[i][1] + bb.y, 0.f);
        h.z = fmaxf(accH[i][2] + bb.z, 0.f);
        h.w = fmaxf(accH[i][3] + bb.w, 0.f);
        *(float4*)&Hs[r0 + i][c0] = h;
      }
    }

    __syncthreads();   // phase-1 reads of Bs done, Hs written
    // stage W2 chunk: 64 k-rows x 64 cols (BOT=64 full width)
    #pragma unroll
    for (int m = 0; m < 4; ++m) {
      int idx = m * 256 + t;
      int k = idx >> 4, c4 = idx & 15;
      float4 v = *(const float4*)(W2 + (size_t)(ch * 64 + k) * BOT + c4 * 4);
      *(float4*)&Bs[k][c4 * 4] = v;
    }
    __syncthreads();

    // ---- phase 2: Out += Hs @ W2chunk ----
    #pragma unroll 4
    for (int k = 0; k < 64; k += 4) {
      float4 a0 = *(const float4*)&Hs[r0 + 0][k];
      float4 a1 = *(const float4*)&Hs[r0 + 1][k];
      float4 a2 = *(const float4*)&Hs[r0 + 2][k];
      float4 a3 = *(const float4*)&Hs[r0 + 3][k];
      float4 b0 = *(const float4*)&Bs[k + 0][c0];
      float4 b1 = *(const float4*)&Bs[k + 1][c0];
      float4 b2 = *(const float4*)&Bs[k + 2][c0];
      float4 b3 = *(const float4*)&Bs[k + 3][c0];
      float ar[4][4] = {{a0.x, a0.y, a0.z, a0.w},
                        {a1.x, a1.y, a1.z, a1.w},
                        {a2.x, a2.y, a2.z, a2.w},
                        {a3.x, a3.y, a3.z, a3.w}};
      #pragma unroll
      for (int i = 0; i < 4; ++i) {
        acc2[i][0] = fmaf(ar[i][0], b0.x, acc2[i][0]);
        acc2[i][1] = fmaf(ar[i][0], b0.y, acc2[i][1]);
        acc2[i][2] = fmaf(ar[i][0], b0.z, acc2[i][2]);
        acc2[i][3] = fmaf(ar[i][0], b0.w, acc2[i][3]);
        acc2[i][0] = fmaf(ar[i][1], b1.x, acc2[i][0]);
        acc2[i][1] = fmaf(ar[i][1], b1.y, acc2[i][1]);
        acc2[i][2] = fmaf(ar[i][1], b1.z, acc2[i][2]);
        acc2[i][3] = fmaf(ar[i][1], b1.w, acc2[i][3]);
        acc2[i][0] = fmaf(ar[i][2], b2.x, acc2[i][0]);
        acc2[i][1] = fmaf(ar[i][2], b2.y, acc2[i][1]);
        acc2[i][2] = fmaf(ar[i][2], b2.z, acc2[i][2]);
        acc2[i][3] = fmaf(ar[i][2], b2.w, acc2[i][3]);
        acc2[i][0] = fmaf(ar[i][3], b3.x, acc2[i][0]);
        acc2[i][1] = fmaf(ar[i][3], b3.y, acc2[i][1]);
        acc2[i][2] = fmaf(ar[i][3], b3.z, acc2[i][2]);
        acc2[i][3] = fmaf(ar[i][3], b3.w, acc2[i][3]);
      }
    }
    __syncthreads();   // done reading Hs before next chunk overwrites
  }

  float4 bb2 = *(const float4*)(B2 + c0);
  #pragma unroll
  for (int i = 0; i < 4; ++i) {
    int gr = rbase + r0 + i;
    if (gr < M) {
      float4 o;
      o.x = acc2[i][0] + bb2.x;
      o.y = acc2[i][1] + bb2.y;
      o.z = acc2[i][2] + bb2.z;
      o.w = acc2[i][3] + bb2.w;
      *(float4*)(Out + (size_t)gr * BOT + c0) = o;
    }
  }
}

// ---------------- aggregate: Xo = relu(norm[i]*(y_i + sum y_src) + b) ----------------

__global__ __launch_bounds__(256) void k_agg(const float* __restrict__ Y,
                                             const int* __restrict__ rowptr, const int* __restrict__ col,
                                             const float* __restrict__ nrm, const float* __restrict__ bias,
                                             float* __restrict__ Xo, int n) {
  int wid = (blockIdx.x * 256 + threadIdx.x) >> 6;
  int lane = threadIdx.x & 63;
  if (wid >= n) return;
  const float2* Yv = (const float2*)Y;
  float2 s0 = Yv[(size_t)wid * 64 + lane];     // self term
  float2 s1 = make_float2(0.f, 0.f);
  float2 s2 = make_float2(0.f, 0.f);
  float2 s3 = make_float2(0.f, 0.f);
  int e0 = rowptr[wid], e1 = rowptr[wid + 1];
  int e = e0;
  for (; e + 4 <= e1; e += 4) {
    int c0 = col[e], c1 = col[e + 1], c2 = col[e + 2], c3 = col[e + 3];
    float2 v0 = Yv[(size_t)c0 * 64 + lane];
    float2 v1 = Yv[(size_t)c1 * 64 + lane];
    float2 v2 = Yv[(size_t)c2 * 64 + lane];
    float2 v3 = Yv[(size_t)c3 * 64 + lane];
    s0.x += v0.x; s0.y += v0.y;
    s1.x += v1.x; s1.y += v1.y;
    s2.x += v2.x; s2.y += v2.y;
    s3.x += v3.x; s3.y += v3.y;
  }
  for (; e < e1; ++e) {
    int c = col[e];
    float2 v = Yv[(size_t)c * 64 + lane];
    s0.x += v.x; s0.y += v.y;
  }
  float2 s;
  s.x = (s0.x + s1.x) + (s2.x + s3.x);
  s.y = (s0.y + s1.y) + (s2.y + s3.y);
  float nm = nrm[wid];
  float2 bb = ((const float2*)bias)[lane];
  float2 o;
  o.x = fmaxf(fmaf(s.x, nm, bb.x), 0.f);
  o.y = fmaxf(fmaf(s.y, nm, bb.y), 0.f);
  ((float2*)Xo)[(size_t)wid * 64 + lane] = o;
}

extern "C" void kernel_launch(void* const* d_in, const int* in_sizes, int n_in,
                              void* d_out, int out_size, void* d_ws, size_t ws_size,
                              hipStream_t stream) {
  const float* x     = (const float*)d_in[0];
  const int*   ei    = (const int*)d_in[1];
  const float* convW = (const float*)d_in[2];
  const float* convB = (const float*)d_in[3];
  const float* w1    = (const float*)d_in[4];
  const float* b1    = (const float*)d_in[5];
  const float* w2    = (const float*)d_in[6];
  const float* b2    = (const float*)d_in[7];
  float* out = (float*)d_out;

  int N = in_sizes[0] / D;
  int E = in_sizes[1] / 2;
  int L = in_sizes[2] / (D * D);

  char* ws = (char*)d_ws;
  size_t off = 0;
  auto alloc = [&](size_t bytes) -> char* {
    char* p = ws + off;
    off += (bytes + 255) & ~(size_t)255;
    return p;
  };
  float* nrm   = (float*)alloc((size_t)N * 4);
  int* cnt     = (int*)alloc((size_t)N * 4);
  int* part    = (int*)alloc((size_t)N * 4);
  int* rowptr  = (int*)alloc((size_t)(N + 1) * 4);
  int* cursor  = (int*)alloc((size_t)N * 4);
  int* bsum    = (int*)alloc(256 * 4);
  int* boff    = (int*)alloc(256 * 4);
  int* col     = (int*)alloc((size_t)E * 4);
  float* bufA  = (float*)alloc((size_t)N * D * 4);
  float* bufB  = (float*)alloc((size_t)N * D * 4);

  int gN = (N + 255) / 256;
  int gE = (E + 255) / 256;

  hipMemsetAsync(cnt, 0, (size_t)N * 4, stream);
  k_hist<<<gE, 256, 0, stream>>>(ei, cnt, E);
  k_scan1<<<gN, 256, 0, stream>>>(cnt, part, bsum, N);
  k_scan2<<<1, 256, 0, stream>>>(bsum, boff, gN);
  k_scan3<<<gN, 256, 0, stream>>>(part, boff, cnt, nrm, rowptr, cursor, N, E);
  k_fill<<<gE, 256, 0, stream>>>(ei, cursor, col, E);

  int nRBf = (N + 63) / 64;
  const float* xin = x;
  for (int l = 0; l < L; ++l) {
    k_gemm64<0><<<nRBf * (D / 64), 256, 0, stream>>>(
        xin, convW + (size_t)l * D * D, nrm, bufA, N, D, D, D, nRBf);
    k_agg<<<(N + 3) / 4, 256, 0, stream>>>(bufA, rowptr, col, nrm, convB + (size_t)l * D, bufB, N);
    xin = bufB;
  }

  k_mlp2<<<nRBf, 256, 0, stream>>>(xin, w1, b1, w2, b2, out, N);
}

// Round 5
// 494.633 us; speedup vs baseline: 1.5054x; 1.1278x over previous
//
#include <hip/hip_runtime.h>
#include <hip/hip_fp16.h>

#define D 128
#define FFN 512
#define BOT 64

// ---------------- CSR build ----------------

__global__ __launch_bounds__(256) void k_hist(const int* __restrict__ ei, int* __restrict__ cnt, int nE) {
  int i = blockIdx.x * 256 + threadIdx.x;
  if (i < nE) atomicAdd(&cnt[ei[nE + i]], 1);   // dst = ei[E + i]
}

__global__ __launch_bounds__(256) void k_scan1(const int* __restrict__ cnt, int* __restrict__ part,
                                               int* __restrict__ bsum, int n) {
  __shared__ int s[256];
  int t = threadIdx.x;
  int i = blockIdx.x * 256 + t;
  int v = (i < n) ? cnt[i] : 0;
  s[t] = v;
  __syncthreads();
  for (int d = 1; d < 256; d <<= 1) {
    int add = (t >= d) ? s[t - d] : 0;
    __syncthreads();
    s[t] += add;
    __syncthreads();
  }
  if (i < n) part[i] = s[t] - v;
  if (t == 255) bsum[blockIdx.x] = s[255];
}

__global__ __launch_bounds__(256) void k_scan2(const int* __restrict__ bsum, int* __restrict__ boff, int nb) {
  __shared__ int s[256];
  int t = threadIdx.x;
  int v = (t < nb) ? bsum[t] : 0;
  s[t] = v;
  __syncthreads();
  for (int d = 1; d < 256; d <<= 1) {
    int add = (t >= d) ? s[t - d] : 0;
    __syncthreads();
    s[t] += add;
    __syncthreads();
  }
  boff[t] = s[t] - v;
}

__global__ __launch_bounds__(256) void k_scan3(const int* __restrict__ part, const int* __restrict__ boff,
                                               const int* __restrict__ cnt, float* __restrict__ nrm,
                                               int* __restrict__ rowptr, int* __restrict__ cursor,
                                               int n, int nE) {
  int i = blockIdx.x * 256 + threadIdx.x;
  if (i < n) {
    int r = part[i] + boff[i >> 8];
    rowptr[i] = r;
    cursor[i] = r;
    nrm[i] = rsqrtf((float)cnt[i] + 1.0f);
  }
  if (i == 0) rowptr[n] = nE;
}

__global__ __launch_bounds__(256) void k_fill(const int* __restrict__ ei, int* __restrict__ cursor,
                                              int* __restrict__ col, int nE) {
  int i = blockIdx.x * 256 + threadIdx.x;
  if (i < nE) {
    int s = ei[i];
    int d2 = ei[nE + i];
    int pos = atomicAdd(&cursor[d2], 1);
    col[pos] = s;
  }
}

// ---------------- 8x8-tile fp32 GEMM, 128-row blocks ----------------
// C[M x *] = A[M x K] @ B[K x ldb], BN-col panel per block.
// A staged TRANSPOSED in K-panels of 32 (AsT[k][r]: b128 column reads).
// B staged with additive bank-skew off(c) = c + (c>>3)*4 -> <=2-way conflicts.
// Thread tile: 8 rows x (BN==128 ? 8 : 4) cols. 0.25 floats/FMA from LDS.
// MODE 0: half out, acc * aux[row]      (conv: Y = XW * nrm)
// MODE 1: half out, relu(acc + aux[col]) (fc1 -> H)
// MODE 2: float out, acc + aux[col]      (fc2)

template<typename AT, int BN, int MODE>
__global__ __launch_bounds__(256, 3) void k_gemm8(const AT* __restrict__ A,
                                                  const float* __restrict__ B,
                                                  const float* __restrict__ aux,
                                                  void* __restrict__ Cout,
                                                  int M, int K, int ldb, int ldc, int nRB) {
  constexpr int AP = (sizeof(AT) == 4) ? 132 : 136;   // pad: 16B-aligned rows
  constexpr int BP = (BN * 3) / 2;                    // skewed pitch: 192 / 96
  constexpr int TN = (BN == 128) ? 8 : 4;
  __shared__ AT    AsT[32][AP];
  __shared__ float Bs[32][BP];

  const int t = threadIdx.x;
  const int rb = blockIdx.x % nRB, cb = blockIdx.x / nRB;
  const int rbase = rb * 128, cbase = cb * BN;
  const int rg = t >> 4, cg = t & 15;
  const int r0 = rg * 8;
  const int c0 = cg * TN;
  const int c0s = c0 + ((c0 >> 3) << 2);

  float acc[8][TN];
  #pragma unroll
  for (int i = 0; i < 8; ++i)
    #pragma unroll
    for (int j = 0; j < TN; ++j) acc[i][j] = 0.f;

  for (int kc = 0; kc < K; kc += 32) {
    __syncthreads();
    // ---- stage A panel (128 x 32), transposed into AsT ----
    #pragma unroll
    for (int m = 0; m < 4; ++m) {
      int idx = m * 256 + t;
      int ar = idx >> 3, kq = idx & 7;
      int gr = rbase + ar;
      AT q[4];
      if (gr < M) {
        if constexpr (sizeof(AT) == 4) {
          float4 v = *(const float4*)(A + (size_t)gr * K + kc + kq * 4);
          q[0] = v.x; q[1] = v.y; q[2] = v.z; q[3] = v.w;
        } else {
          float2 v = *(const float2*)(A + (size_t)gr * K + kc + kq * 4);
          const __half* hp = (const __half*)&v;
          q[0] = hp[0]; q[1] = hp[1]; q[2] = hp[2]; q[3] = hp[3];
        }
      } else {
        q[0] = (AT)0.f; q[1] = (AT)0.f; q[2] = (AT)0.f; q[3] = (AT)0.f;
      }
      #pragma unroll
      for (int j = 0; j < 4; ++j) AsT[kq * 4 + j][ar] = q[j];
    }
    // ---- stage B panel (32 x BN), skewed ----
    #pragma unroll
    for (int m = 0; m < (32 * BN / 4) / 256; ++m) {
      int idx = m * 256 + t;
      int row = (BN == 128) ? (idx >> 5) : (idx >> 4);
      int c4  = (BN == 128) ? (idx & 31) : (idx & 15);
      float4 v = *(const float4*)(B + (size_t)(kc + row) * ldb + cbase + c4 * 4);
      int off = c4 * 4 + ((c4 >> 1) << 2);
      *(float4*)&Bs[row][off] = v;
    }
    __syncthreads();

    #pragma unroll 4
    for (int k = 0; k < 32; ++k) {
      float af[8];
      if constexpr (sizeof(AT) == 4) {
        float4 x0 = *(const float4*)&AsT[k][r0];
        float4 x1 = *(const float4*)&AsT[k][r0 + 4];
        af[0] = x0.x; af[1] = x0.y; af[2] = x0.z; af[3] = x0.w;
        af[4] = x1.x; af[5] = x1.y; af[6] = x1.z; af[7] = x1.w;
      } else {
        float4 hv = *(const float4*)&AsT[k][r0];
        const __half2* hp = (const __half2*)&hv;
        float2 f0 = __half22float2(hp[0]);
        float2 f1 = __half22float2(hp[1]);
        float2 f2 = __half22float2(hp[2]);
        float2 f3 = __half22float2(hp[3]);
        af[0] = f0.x; af[1] = f0.y; af[2] = f1.x; af[3] = f1.y;
        af[4] = f2.x; af[5] = f2.y; af[6] = f3.x; af[7] = f3.y;
      }
      float4 b0 = *(const float4*)&Bs[k][c0s];
      float bf[TN];
      bf[0] = b0.x; bf[1] = b0.y; bf[2] = b0.z; bf[3] = b0.w;
      if constexpr (TN == 8) {
        float4 b1 = *(const float4*)&Bs[k][c0s + 4];
        bf[4] = b1.x; bf[5] = b1.y; bf[6] = b1.z; bf[7] = b1.w;
      }
      #pragma unroll
      for (int i = 0; i < 8; ++i)
        #pragma unroll
        for (int j = 0; j < TN; ++j)
          acc[i][j] = fmaf(af[i], bf[j], acc[i][j]);
    }
  }

  if constexpr (MODE == 0) {
    __half* Ch = (__half*)Cout;
    #pragma unroll
    for (int i = 0; i < 8; ++i) {
      int gr = rbase + r0 + i;
      if (gr < M) {
        float s = aux[gr];
        __half2 o[4];
        #pragma unroll
        for (int q = 0; q < 4; ++q)
          o[q] = __floats2half2_rn(acc[i][2 * q] * s, acc[i][2 * q + 1] * s);
        *(float4*)(Ch + (size_t)gr * ldc + cbase + c0) = *(float4*)o;
      }
    }
  } else if constexpr (MODE == 1) {
    __half* Ch = (__half*)Cout;
    float4 bb0 = *(const float4*)(aux + cbase + c0);
    float4 bb1 = *(const float4*)(aux + cbase + c0 + 4);
    float bb[8] = {bb0.x, bb0.y, bb0.z, bb0.w, bb1.x, bb1.y, bb1.z, bb1.w};
    #pragma unroll
    for (int i = 0; i < 8; ++i) {
      int gr = rbase + r0 + i;
      if (gr < M) {
        __half2 o[4];
        #pragma unroll
        for (int q = 0; q < 4; ++q) {
          float a = fmaxf(acc[i][2 * q] + bb[2 * q], 0.f);
          float b = fmaxf(acc[i][2 * q + 1] + bb[2 * q + 1], 0.f);
          o[q] = __floats2half2_rn(a, b);
        }
        *(float4*)(Ch + (size_t)gr * ldc + cbase + c0) = *(float4*)o;
      }
    }
  } else {
    float* Cf = (float*)Cout;
    float4 bb = *(const float4*)(aux + cbase + c0);
    #pragma unroll
    for (int i = 0; i < 8; ++i) {
      int gr = rbase + r0 + i;
      if (gr < M) {
        float4 o;
        o.x = acc[i][0] + bb.x;
        o.y = acc[i][1] + bb.y;
        o.z = acc[i][2] + bb.z;
        o.w = acc[i][3] + bb.w;
        *(float4*)(Cf + (size_t)gr * ldc + cbase + c0) = o;
      }
    }
  }
}

// ---------------- aggregate: Xo = relu(norm[i]*(y_i + sum y_src) + b) ----------------
// Y is fp16 (half2 per lane, 64 lanes = 256B row); accumulate fp32; Xo fp32.

__global__ __launch_bounds__(256) void k_agg(const __half* __restrict__ Y,
                                             const int* __restrict__ rowptr, const int* __restrict__ col,
                                             const float* __restrict__ nrm, const float* __restrict__ bias,
                                             float* __restrict__ Xo, int n) {
  int wid = (blockIdx.x * 256 + threadIdx.x) >> 6;
  int lane = threadIdx.x & 63;
  if (wid >= n) return;
  const __half2* Yv = (const __half2*)Y;
  float2 s0 = __half22float2(Yv[(size_t)wid * 64 + lane]);   // self term
  float2 s1 = make_float2(0.f, 0.f);
  float2 s2 = make_float2(0.f, 0.f);
  float2 s3 = make_float2(0.f, 0.f);
  int e0 = rowptr[wid], e1 = rowptr[wid + 1];
  int e = e0;
  for (; e + 4 <= e1; e += 4) {
    int c0 = col[e], c1 = col[e + 1], c2 = col[e + 2], c3 = col[e + 3];
    float2 v0 = __half22float2(Yv[(size_t)c0 * 64 + lane]);
    float2 v1 = __half22float2(Yv[(size_t)c1 * 64 + lane]);
    float2 v2 = __half22float2(Yv[(size_t)c2 * 64 + lane]);
    float2 v3 = __half22float2(Yv[(size_t)c3 * 64 + lane]);
    s0.x += v0.x; s0.y += v0.y;
    s1.x += v1.x; s1.y += v1.y;
    s2.x += v2.x; s2.y += v2.y;
    s3.x += v3.x; s3.y += v3.y;
  }
  for (; e < e1; ++e) {
    int c = col[e];
    float2 v = __half22float2(Yv[(size_t)c * 64 + lane]);
    s0.x += v.x; s0.y += v.y;
  }
  float2 s;
  s.x = (s0.x + s1.x) + (s2.x + s3.x);
  s.y = (s0.y + s1.y) + (s2.y + s3.y);
  float nm = nrm[wid];
  float2 bb = ((const float2*)bias)[lane];
  float2 o;
  o.x = fmaxf(fmaf(s.x, nm, bb.x), 0.f);
  o.y = fmaxf(fmaf(s.y, nm, bb.y), 0.f);
  ((float2*)Xo)[(size_t)wid * 64 + lane] = o;
}

extern "C" void kernel_launch(void* const* d_in, const int* in_sizes, int n_in,
                              void* d_out, int out_size, void* d_ws, size_t ws_size,
                              hipStream_t stream) {
  const float* x     = (const float*)d_in[0];
  const int*   ei    = (const int*)d_in[1];
  const float* convW = (const float*)d_in[2];
  const float* convB = (const float*)d_in[3];
  const float* w1    = (const float*)d_in[4];
  const float* b1    = (const float*)d_in[5];
  const float* w2    = (const float*)d_in[6];
  const float* b2    = (const float*)d_in[7];
  float* out = (float*)d_out;

  int N = in_sizes[0] / D;
  int E = in_sizes[1] / 2;
  int L = in_sizes[2] / (D * D);

  char* ws = (char*)d_ws;
  size_t off = 0;
  auto alloc = [&](size_t bytes) -> char* {
    char* p = ws + off;
    off += (bytes + 255) & ~(size_t)255;
    return p;
  };
  float*  nrm    = (float*)alloc((size_t)N * 4);
  int*    cnt    = (int*)alloc((size_t)N * 4);
  int*    part   = (int*)alloc((size_t)N * 4);
  int*    rowptr = (int*)alloc((size_t)(N + 1) * 4);
  int*    cursor = (int*)alloc((size_t)N * 4);
  int*    bsum   = (int*)alloc(256 * 4);
  int*    boff   = (int*)alloc(256 * 4);
  int*    col    = (int*)alloc((size_t)E * 4);
  __half* Yh     = (__half*)alloc((size_t)N * D * 2);        // conv output, fp16
  float*  Xb     = (float*)alloc((size_t)N * D * 4);         // aggregated X', fp32
  __half* Hh     = (__half*)alloc((size_t)N * FFN * 2);      // MLP hidden, fp16

  int gN = (N + 255) / 256;
  int gE = (E + 255) / 256;

  hipMemsetAsync(cnt, 0, (size_t)N * 4, stream);
  k_hist<<<gE, 256, 0, stream>>>(ei, cnt, E);
  k_scan1<<<gN, 256, 0, stream>>>(cnt, part, bsum, N);
  k_scan2<<<1, 256, 0, stream>>>(bsum, boff, gN);
  k_scan3<<<gN, 256, 0, stream>>>(part, boff, cnt, nrm, rowptr, cursor, N, E);
  k_fill<<<gE, 256, 0, stream>>>(ei, cursor, col, E);

  int nRB = (N + 127) / 128;
  const float* xin = x;
  for (int l = 0; l < L; ++l) {
    k_gemm8<float, 128, 0><<<nRB, 256, 0, stream>>>(
        xin, convW + (size_t)l * D * D, nrm, Yh, N, D, D, D, nRB);
    k_agg<<<(N + 3) / 4, 256, 0, stream>>>(Yh, rowptr, col, nrm, convB + (size_t)l * D, Xb, N);
    xin = Xb;
  }

  // MLP: fc1 -> H (fp16), fc2 -> out (fp32)
  k_gemm8<float, 128, 1><<<nRB * (FFN / 128), 256, 0, stream>>>(
      xin, w1, b1, Hh, N, D, FFN, FFN, nRB);
  k_gemm8<__half, 64, 2><<<nRB, 256, 0, stream>>>(
      Hh, w2, b2, out, N, FFN, BOT, BOT, nRB);
}

// Round 7
// 338.305 us; speedup vs baseline: 2.2011x; 1.4621x over previous
//
#include <hip/hip_runtime.h>
#include <hip/hip_fp16.h>

#define D 128
#define FFN 512
#define BOT 64

typedef _Float16 f16x8 __attribute__((ext_vector_type(8)));
typedef float f32x4 __attribute__((ext_vector_type(4)));

// ---------------- CSR build ----------------

__global__ __launch_bounds__(256) void k_hist(const int* __restrict__ ei, int* __restrict__ cnt, int nE) {
  int i = blockIdx.x * 256 + threadIdx.x;
  if (i < nE) atomicAdd(&cnt[ei[nE + i]], 1);   // dst = ei[E + i]
}

__global__ __launch_bounds__(256) void k_scan1(const int* __restrict__ cnt, int* __restrict__ part,
                                               int* __restrict__ bsum, int n) {
  __shared__ int s[256];
  int t = threadIdx.x;
  int i = blockIdx.x * 256 + t;
  int v = (i < n) ? cnt[i] : 0;
  s[t] = v;
  __syncthreads();
  for (int d = 1; d < 256; d <<= 1) {
    int add = (t >= d) ? s[t - d] : 0;
    __syncthreads();
    s[t] += add;
    __syncthreads();
  }
  if (i < n) part[i] = s[t] - v;
  if (t == 255) bsum[blockIdx.x] = s[255];
}

__global__ __launch_bounds__(256) void k_scan2(const int* __restrict__ bsum, int* __restrict__ boff, int nb) {
  __shared__ int s[256];
  int t = threadIdx.x;
  int v = (t < nb) ? bsum[t] : 0;
  s[t] = v;
  __syncthreads();
  for (int d = 1; d < 256; d <<= 1) {
    int add = (t >= d) ? s[t - d] : 0;
    __syncthreads();
    s[t] += add;
    __syncthreads();
  }
  boff[t] = s[t] - v;
}

__global__ __launch_bounds__(256) void k_scan3(const int* __restrict__ part, const int* __restrict__ boff,
                                               const int* __restrict__ cnt, float* __restrict__ nrm,
                                               int* __restrict__ rowptr, int* __restrict__ cursor,
                                               int n, int nE) {
  int i = blockIdx.x * 256 + threadIdx.x;
  if (i < n) {
    int r = part[i] + boff[i >> 8];
    rowptr[i] = r;
    cursor[i] = r;
    nrm[i] = rsqrtf((float)cnt[i] + 1.0f);
  }
  if (i == 0) rowptr[n] = nE;
}

__global__ __launch_bounds__(256) void k_fill(const int* __restrict__ ei, int* __restrict__ cursor,
                                              int* __restrict__ col, int nE) {
  int i = blockIdx.x * 256 + threadIdx.x;
  if (i < nE) {
    int s = ei[i];
    int d2 = ei[nE + i];
    int pos = atomicAdd(&cursor[d2], 1);
    col[pos] = s;
  }
}

// ---------------- split helpers ----------------

__global__ __launch_bounds__(256) void k_split(const float* __restrict__ X,
                                               __half* __restrict__ Xh, __half* __restrict__ Xl, int n8) {
  int i = blockIdx.x * 256 + threadIdx.x;
  if (i >= n8) return;
  float4 a = ((const float4*)X)[i * 2];
  float4 b = ((const float4*)X)[i * 2 + 1];
  float v[8] = {a.x, a.y, a.z, a.w, b.x, b.y, b.z, b.w};
  __half2 hh[4], ll[4];
  #pragma unroll
  for (int q = 0; q < 4; ++q) {
    __half h0 = __float2half_rn(v[2 * q]);
    __half h1 = __float2half_rn(v[2 * q + 1]);
    __half l0 = __float2half_rn(v[2 * q] - __half2float(h0));
    __half l1 = __float2half_rn(v[2 * q + 1] - __half2float(h1));
    hh[q] = __halves2half2(h0, h1);
    ll[q] = __halves2half2(l0, l1);
  }
  *(uint4*)(Xh + (size_t)i * 8) = *(uint4*)hh;
  *(uint4*)(Xl + (size_t)i * 8) = *(uint4*)ll;
}

// W [K x N] fp32 -> WhT/WlT [N x K] fp16 (split + transpose)

__global__ __launch_bounds__(256) void k_splitw(const float* __restrict__ W,
                                                __half* __restrict__ WhT, __half* __restrict__ WlT,
                                                int K, int N) {
  int id = blockIdx.x * 256 + threadIdx.x;
  if (id >= K * N) return;
  int n = id / K, k = id % K;
  float v = W[(size_t)k * N + n];
  __half h = __float2half_rn(v);
  WhT[id] = h;
  WlT[id] = __float2half_rn(v - __half2float(h));
}

// ---------------- MFMA GEMM: C = A @ B with split-fp16 operands ----------------
// acc = Ah*Bh + Ah*Bl (+ Al*Bh if NSPLIT==2), fp32 accum.
// Block = 128 rows x BN cols, 4 waves (2 in m x 2 in n); wave tile 64 x BN/2.
// wc = (wid&1)*(BN/2)   <-- round-6 bug was (wid&1)*64, OOB for BN=64.
// MODE 0: half out = acc * aux[row]; MODE 1: half out = relu(acc+aux[col]);
// MODE 2: float out = acc + aux[col].

template<int BN, int MODE, int NSPLIT>
__global__ __launch_bounds__(256, (BN == 128) ? 3 : 4)
void k_mfma(const __half* __restrict__ Ah_g, const __half* __restrict__ Al_g,
            const __half* __restrict__ BhT_g, const __half* __restrict__ BlT_g,
            const float* __restrict__ aux, void* __restrict__ Cout,
            int M, int K, int ldc, int nRB) {
  constexpr int NR = BN / 32;                    // n-fragments per wave (= (BN/2)/16)
  constexpr int ALR = (NSPLIT == 2) ? 128 : 1;
  __shared__ __half Ahs[128][40];
  __shared__ __half Als[ALR][40];
  __shared__ __half Bhs[BN][40];
  __shared__ __half Bls[BN][40];

  const int t = threadIdx.x;
  const int rb = blockIdx.x % nRB, cb = blockIdx.x / nRB;
  const int rbase = rb * 128, cbase = cb * BN;
  const int lane = t & 63, wid = t >> 6;
  const int wr = (wid >> 1) * 64;
  const int wc = (wid & 1) * (BN / 2);
  const int lr = lane & 15, lq = lane >> 4;

  f32x4 acc[4][NR];
  #pragma unroll
  for (int m = 0; m < 4; ++m)
    #pragma unroll
    for (int n = 0; n < NR; ++n) acc[m][n] = (f32x4){0.f, 0.f, 0.f, 0.f};

  for (int kc = 0; kc < K; kc += 32) {
    __syncthreads();
    // stage A panel: 128 rows x 32 k
    #pragma unroll
    for (int mm = 0; mm < 2; ++mm) {
      int idx = mm * 256 + t;
      int row = idx >> 2, q = idx & 3;
      int gr = rbase + row;
      uint4 vh = {0, 0, 0, 0};
      if (gr < M) vh = *(const uint4*)(Ah_g + (size_t)gr * K + kc + q * 8);
      *(uint4*)&Ahs[row][q * 8] = vh;
      if constexpr (NSPLIT == 2) {
        uint4 vl = {0, 0, 0, 0};
        if (gr < M) vl = *(const uint4*)(Al_g + (size_t)gr * K + kc + q * 8);
        *(uint4*)&Als[row][q * 8] = vl;
      }
    }
    // stage B panel: BN cols x 32 k
    #pragma unroll
    for (int mm = 0; mm < BN / 64; ++mm) {
      int idx = mm * 256 + t;
      int c = idx >> 2, q = idx & 3;
      size_t src = (size_t)(cbase + c) * K + kc + q * 8;
      *(uint4*)&Bhs[c][q * 8] = *(const uint4*)(BhT_g + src);
      *(uint4*)&Bls[c][q * 8] = *(const uint4*)(BlT_g + src);
    }
    __syncthreads();

    f16x8 fb[NR], fbl[NR], fa[4];
    #pragma unroll
    for (int n = 0; n < NR; ++n) {
      fb[n]  = *(const f16x8*)&Bhs[wc + n * 16 + lr][lq * 8];
      fbl[n] = *(const f16x8*)&Bls[wc + n * 16 + lr][lq * 8];
    }
    #pragma unroll
    for (int m = 0; m < 4; ++m)
      fa[m] = *(const f16x8*)&Ahs[wr + m * 16 + lr][lq * 8];

    #pragma unroll
    for (int m = 0; m < 4; ++m)
      #pragma unroll
      for (int n = 0; n < NR; ++n) {
        acc[m][n] = __builtin_amdgcn_mfma_f32_16x16x32_f16(fa[m], fb[n], acc[m][n], 0, 0, 0);
        acc[m][n] = __builtin_amdgcn_mfma_f32_16x16x32_f16(fa[m], fbl[n], acc[m][n], 0, 0, 0);
      }

    if constexpr (NSPLIT == 2) {
      f16x8 fal[4];
      #pragma unroll
      for (int m = 0; m < 4; ++m)
        fal[m] = *(const f16x8*)&Als[wr + m * 16 + lr][lq * 8];
      #pragma unroll
      for (int m = 0; m < 4; ++m)
        #pragma unroll
        for (int n = 0; n < NR; ++n)
          acc[m][n] = __builtin_amdgcn_mfma_f32_16x16x32_f16(fal[m], fb[n], acc[m][n], 0, 0, 0);
    }
  }

  // epilogue: C/D frag map (m89-verified): col = lane&15, row = (lane>>4)*4 + j
  if constexpr (MODE == 0) {
    __half* Yo = (__half*)Cout;
    #pragma unroll
    for (int m = 0; m < 4; ++m)
      #pragma unroll
      for (int j = 0; j < 4; ++j) {
        int row = rbase + wr + m * 16 + lq * 4 + j;
        if (row < M) {
          float s = aux[row];
          #pragma unroll
          for (int n = 0; n < NR; ++n) {
            int colg = cbase + wc + n * 16 + lr;
            Yo[(size_t)row * ldc + colg] = __float2half_rn(acc[m][n][j] * s);
          }
        }
      }
  } else {
    float bb[NR];
    #pragma unroll
    for (int n = 0; n < NR; ++n) bb[n] = aux[cbase + wc + n * 16 + lr];
    if constexpr (MODE == 1) {
      __half* Yo = (__half*)Cout;
      #pragma unroll
      for (int m = 0; m < 4; ++m)
        #pragma unroll
        for (int j = 0; j < 4; ++j) {
          int row = rbase + wr + m * 16 + lq * 4 + j;
          if (row < M) {
            #pragma unroll
            for (int n = 0; n < NR; ++n) {
              int colg = cbase + wc + n * 16 + lr;
              Yo[(size_t)row * ldc + colg] = __float2half_rn(fmaxf(acc[m][n][j] + bb[n], 0.f));
            }
          }
        }
    } else {
      float* Of = (float*)Cout;
      #pragma unroll
      for (int m = 0; m < 4; ++m)
        #pragma unroll
        for (int j = 0; j < 4; ++j) {
          int row = rbase + wr + m * 16 + lq * 4 + j;
          if (row < M) {
            #pragma unroll
            for (int n = 0; n < NR; ++n) {
              int colg = cbase + wc + n * 16 + lr;
              Of[(size_t)row * ldc + colg] = acc[m][n][j] + bb[n];
            }
          }
        }
    }
  }
}

// ---------------- aggregate: X' = relu(norm[i]*(y_i + sum y_src) + b), split output ----------------

__global__ __launch_bounds__(256) void k_agg(const __half* __restrict__ Y,
                                             const int* __restrict__ rowptr, const int* __restrict__ col,
                                             const float* __restrict__ nrm, const float* __restrict__ bias,
                                             __half2* __restrict__ Xh2, __half2* __restrict__ Xl2, int n) {
  int wid = (blockIdx.x * 256 + threadIdx.x) >> 6;
  int lane = threadIdx.x & 63;
  if (wid >= n) return;
  const __half2* Yv = (const __half2*)Y;
  float2 s0 = __half22float2(Yv[(size_t)wid * 64 + lane]);   // self term
  float2 s1 = make_float2(0.f, 0.f);
  float2 s2 = make_float2(0.f, 0.f);
  float2 s3 = make_float2(0.f, 0.f);
  int e0 = rowptr[wid], e1 = rowptr[wid + 1];
  int e = e0;
  for (; e + 4 <= e1; e += 4) {
    int c0 = col[e], c1 = col[e + 1], c2 = col[e + 2], c3 = col[e + 3];
    float2 v0 = __half22float2(Yv[(size_t)c0 * 64 + lane]);
    float2 v1 = __half22float2(Yv[(size_t)c1 * 64 + lane]);
    float2 v2 = __half22float2(Yv[(size_t)c2 * 64 + lane]);
    float2 v3 = __half22float2(Yv[(size_t)c3 * 64 + lane]);
    s0.x += v0.x; s0.y += v0.y;
    s1.x += v1.x; s1.y += v1.y;
    s2.x += v2.x; s2.y += v2.y;
    s3.x += v3.x; s3.y += v3.y;
  }
  for (; e < e1; ++e) {
    int c = col[e];
    float2 v = __half22float2(Yv[(size_t)c * 64 + lane]);
    s0.x += v.x; s0.y += v.y;
  }
  float2 s;
  s.x = (s0.x + s1.x) + (s2.x + s3.x);
  s.y = (s0.y + s1.y) + (s2.y + s3.y);
  float nm = nrm[wid];
  float2 bb = ((const float2*)bias)[lane];
  float ox = fmaxf(fmaf(s.x, nm, bb.x), 0.f);
  float oy = fmaxf(fmaf(s.y, nm, bb.y), 0.f);
  __half hx = __float2half_rn(ox), hy = __float2half_rn(oy);
  __half lx = __float2half_rn(ox - __half2float(hx));
  __half ly = __float2half_rn(oy - __half2float(hy));
  size_t idx = (size_t)wid * 64 + lane;
  Xh2[idx] = __halves2half2(hx, hy);
  Xl2[idx] = __halves2half2(lx, ly);
}

extern "C" void kernel_launch(void* const* d_in, const int* in_sizes, int n_in,
                              void* d_out, int out_size, void* d_ws, size_t ws_size,
                              hipStream_t stream) {
  const float* x     = (const float*)d_in[0];
  const int*   ei    = (const int*)d_in[1];
  const float* convW = (const float*)d_in[2];
  const float* convB = (const float*)d_in[3];
  const float* w1    = (const float*)d_in[4];
  const float* b1    = (const float*)d_in[5];
  const float* w2    = (const float*)d_in[6];
  const float* b2    = (const float*)d_in[7];
  float* out = (float*)d_out;

  int N = in_sizes[0] / D;
  int E = in_sizes[1] / 2;
  int L = in_sizes[2] / (D * D);

  char* ws = (char*)d_ws;
  size_t off = 0;
  auto alloc = [&](size_t bytes) -> char* {
    char* p = ws + off;
    off += (bytes + 255) & ~(size_t)255;
    return p;
  };
  float*  nrm    = (float*)alloc((size_t)N * 4);
  int*    cnt    = (int*)alloc((size_t)N * 4);
  int*    part   = (int*)alloc((size_t)N * 4);
  int*    rowptr = (int*)alloc((size_t)(N + 1) * 4);
  int*    cursor = (int*)alloc((size_t)N * 4);
  int*    bsum   = (int*)alloc(256 * 4);
  int*    boff   = (int*)alloc(256 * 4);
  int*    col    = (int*)alloc((size_t)E * 4);
  __half* Xh     = (__half*)alloc((size_t)N * D * 2);
  __half* Xl     = (__half*)alloc((size_t)N * D * 2);
  __half* Yh     = (__half*)alloc((size_t)N * D * 2);
  __half* Hh     = (__half*)alloc((size_t)N * FFN * 2);
  __half* WcTh   = (__half*)alloc((size_t)L * D * D * 2);
  __half* WcTl   = (__half*)alloc((size_t)L * D * D * 2);
  __half* W1Th   = (__half*)alloc((size_t)D * FFN * 2);
  __half* W1Tl   = (__half*)alloc((size_t)D * FFN * 2);
  __half* W2Th   = (__half*)alloc((size_t)FFN * BOT * 2);
  __half* W2Tl   = (__half*)alloc((size_t)FFN * BOT * 2);

  int gN = (N + 255) / 256;
  int gE = (E + 255) / 256;

  hipMemsetAsync(cnt, 0, (size_t)N * 4, stream);
  k_hist<<<gE, 256, 0, stream>>>(ei, cnt, E);
  k_scan1<<<gN, 256, 0, stream>>>(cnt, part, bsum, N);
  k_scan2<<<1, 256, 0, stream>>>(bsum, boff, gN);
  k_scan3<<<gN, 256, 0, stream>>>(part, boff, cnt, nrm, rowptr, cursor, N, E);
  k_fill<<<gE, 256, 0, stream>>>(ei, cursor, col, E);

  // operand prep: split x, split+transpose all weights
  int n8 = N * D / 8;
  k_split<<<(n8 + 255) / 256, 256, 0, stream>>>(x, Xh, Xl, n8);
  for (int l = 0; l < L; ++l)
    k_splitw<<<(D * D + 255) / 256, 256, 0, stream>>>(
        convW + (size_t)l * D * D, WcTh + (size_t)l * D * D, WcTl + (size_t)l * D * D, D, D);
  k_splitw<<<(D * FFN + 255) / 256, 256, 0, stream>>>(w1, W1Th, W1Tl, D, FFN);
  k_splitw<<<(FFN * BOT + 255) / 256, 256, 0, stream>>>(w2, W2Th, W2Tl, FFN, BOT);

  int nRB = (N + 127) / 128;
  for (int l = 0; l < L; ++l) {
    k_mfma<128, 0, 2><<<nRB, 256, 0, stream>>>(
        Xh, Xl, WcTh + (size_t)l * D * D, WcTl + (size_t)l * D * D, nrm, Yh, N, D, D, nRB);
    k_agg<<<(N + 3) / 4, 256, 0, stream>>>(Yh, rowptr, col, nrm, convB + (size_t)l * D,
                                           (__half2*)Xh, (__half2*)Xl, N);
  }

  // fc1: H = relu(X@W1+b1) fp16 ; fc2: out = H@W2+b2 fp32
  k_mfma<128, 1, 2><<<nRB * (FFN / 128), 256, 0, stream>>>(
      Xh, Xl, W1Th, W1Tl, b1, Hh, N, D, FFN, nRB);
  k_mfma<64, 2, 1><<<nRB, 256, 0, stream>>>(
      Hh, (const __half*)nullptr, W2Th, W2Tl, b2, out, N, FFN, BOT, nRB);
}

// Round 8
// 282.334 us; speedup vs baseline: 2.6374x; 1.1982x over previous
//
#include <hip/hip_runtime.h>
#include <hip/hip_fp16.h>

#define D 128
#define FFN 512
#define BOT 64
#define EPB 4096      // edges per bucketing block

typedef _Float16 f16x8 __attribute__((ext_vector_type(8)));
typedef float f32x4 __attribute__((ext_vector_type(4)));

// ================ CSR build via bucketed counting sort ================
// bucket = dst >> 8 (256 nodes per bucket), NBKT = ceil(N/256) <= 256.

// stage 1: global bucket counts (LDS-aggregated)
__global__ __launch_bounds__(256) void k_bcnt(const int* __restrict__ dst, int* __restrict__ bcnt, int nE) {
  __shared__ int h[256];
  int t = threadIdx.x;
  h[t] = 0;
  __syncthreads();
  int base = blockIdx.x * EPB;
  #pragma unroll
  for (int m = 0; m < EPB / 256; ++m) {
    int idx = base + m * 256 + t;
    if (idx < nE) atomicAdd(&h[dst[idx] >> 8], 1);
  }
  __syncthreads();
  if (h[t] > 0) atomicAdd(&bcnt[t], h[t]);
}

// stage 2: scan bucket counts -> bucketOff (exclusive), init cursor
__global__ __launch_bounds__(256) void k_bscan(const int* __restrict__ bcnt, int* __restrict__ boff,
                                               int* __restrict__ bcur, int nbkt, int nE) {
  __shared__ int s[256];
  int t = threadIdx.x;
  int v = (t < nbkt) ? bcnt[t] : 0;
  s[t] = v;
  __syncthreads();
  for (int d = 1; d < 256; d <<= 1) {
    int add = (t >= d) ? s[t - d] : 0;
    __syncthreads();
    s[t] += add;
    __syncthreads();
  }
  int ex = s[t] - v;
  boff[t] = ex;
  bcur[t] = ex;
  if (t == 255) boff[256] = nE;   // boff[b] for b >= nbkt equals nE anyway; ensure [nbkt] covered
  if (t >= nbkt) boff[t] = nE;
}

// stage 3: scatter edges into bucket-grouped array with block-local sorting
__global__ __launch_bounds__(256) void k_bscatter(const int* __restrict__ ei, int* __restrict__ bcur,
                                                  uint2* __restrict__ bed, int nE) {
  __shared__ uint2 st[EPB];
  __shared__ int cnt[256], off[256], base[256], cur[256];
  int t = threadIdx.x;
  int blk0 = blockIdx.x * EPB;
  int nblk = nE - blk0;
  if (nblk > EPB) nblk = EPB;

  cnt[t] = 0;
  cur[t] = 0;
  __syncthreads();

  int rs[EPB / 256], rd[EPB / 256];
  #pragma unroll
  for (int m = 0; m < EPB / 256; ++m) {
    int idx = blk0 + m * 256 + t;
    if (idx < nE) {
      rs[m] = ei[idx];
      rd[m] = ei[nE + idx];
      atomicAdd(&cnt[rd[m] >> 8], 1);
    } else {
      rd[m] = -1;
    }
  }
  __syncthreads();

  // scan cnt -> off (exclusive)
  int v = cnt[t];
  off[t] = v;
  __syncthreads();
  for (int d = 1; d < 256; d <<= 1) {
    int add = (t >= d) ? off[t - d] : 0;
    __syncthreads();
    off[t] += add;
    __syncthreads();
  }
  int ex = off[t] - v;
  __syncthreads();
  off[t] = ex;
  // reserve global range for this block's bucket-t edges
  base[t] = (v > 0) ? atomicAdd(&bcur[t], v) : 0;
  __syncthreads();

  // stage pairs sorted by bucket
  #pragma unroll
  for (int m = 0; m < EPB / 256; ++m) {
    if (rd[m] >= 0) {
      int b = rd[m] >> 8;
      int p = off[b] + atomicAdd(&cur[b], 1);
      st[p] = make_uint2((unsigned)rs[m], (unsigned)rd[m]);
    }
  }
  __syncthreads();

  // write out: contiguous per bucket
  for (int j = t; j < nblk; j += 256) {
    uint2 pr = st[j];
    int b = (int)(pr.y >> 8);
    bed[base[b] + (j - off[b])] = pr;
  }
}

// stage 4: per bucket (256 nodes): degree count, scan, rowptr/nrm/col
__global__ __launch_bounds__(256) void k_bcsr(const uint2* __restrict__ bed, const int* __restrict__ boff,
                                              int* __restrict__ rowptr, float* __restrict__ nrm,
                                              int* __restrict__ col, int N, int nE) {
  __shared__ int cnt[256], noff[256], cur[256];
  int t = threadIdx.x;
  int b = blockIdx.x;
  int e0 = boff[b], e1 = boff[b + 1];

  cnt[t] = 0;
  __syncthreads();
  for (int j = e0 + t; j < e1; j += 256)
    atomicAdd(&cnt[bed[j].y & 255], 1);
  __syncthreads();

  int v = cnt[t];
  noff[t] = v;
  __syncthreads();
  for (int d = 1; d < 256; d <<= 1) {
    int add = (t >= d) ? noff[t - d] : 0;
    __syncthreads();
    noff[t] += add;
    __syncthreads();
  }
  int ex = noff[t] - v;
  __syncthreads();
  noff[t] = ex;
  cur[t] = ex;
  __syncthreads();

  int node = (b << 8) + t;
  if (node < N) {
    rowptr[node] = e0 + ex;
    nrm[node] = rsqrtf((float)v + 1.0f);
  }
  if (b == 0 && t == 0) rowptr[N] = nE;

  for (int j = e0 + t; j < e1; j += 256) {
    uint2 pr = bed[j];
    int d2 = (int)(pr.y & 255);
    int p = atomicAdd(&cur[d2], 1);
    col[e0 + p] = (int)pr.x;
  }
}

// ---------------- split helpers ----------------

__global__ __launch_bounds__(256) void k_split(const float* __restrict__ X,
                                               __half* __restrict__ Xh, __half* __restrict__ Xl, int n8) {
  int i = blockIdx.x * 256 + threadIdx.x;
  if (i >= n8) return;
  float4 a = ((const float4*)X)[i * 2];
  float4 b = ((const float4*)X)[i * 2 + 1];
  float v[8] = {a.x, a.y, a.z, a.w, b.x, b.y, b.z, b.w};
  __half2 hh[4], ll[4];
  #pragma unroll
  for (int q = 0; q < 4; ++q) {
    __half h0 = __float2half_rn(v[2 * q]);
    __half h1 = __float2half_rn(v[2 * q + 1]);
    __half l0 = __float2half_rn(v[2 * q] - __half2float(h0));
    __half l1 = __float2half_rn(v[2 * q + 1] - __half2float(h1));
    hh[q] = __halves2half2(h0, h1);
    ll[q] = __halves2half2(l0, l1);
  }
  *(uint4*)(Xh + (size_t)i * 8) = *(uint4*)hh;
  *(uint4*)(Xl + (size_t)i * 8) = *(uint4*)ll;
}

// W [K x N] fp32 -> WhT/WlT [N x K] fp16 (split + transpose)
__global__ __launch_bounds__(256) void k_splitw(const float* __restrict__ W,
                                                __half* __restrict__ WhT, __half* __restrict__ WlT,
                                                int K, int N) {
  int id = blockIdx.x * 256 + threadIdx.x;
  if (id >= K * N) return;
  int n = id / K, k = id % K;
  float v = W[(size_t)k * N + n];
  __half h = __float2half_rn(v);
  WhT[id] = h;
  WlT[id] = __float2half_rn(v - __half2float(h));
}

// all L conv weights (D x D each) in one launch
__global__ __launch_bounds__(256) void k_splitwc(const float* __restrict__ W,
                                                 __half* __restrict__ WhT, __half* __restrict__ WlT,
                                                 int total) {
  int id = blockIdx.x * 256 + threadIdx.x;
  if (id >= total) return;
  int l = id / (D * D), r = id % (D * D);
  int n = r / D, k = r % D;
  float v = W[(size_t)l * D * D + (size_t)k * D + n];
  __half h = __float2half_rn(v);
  WhT[id] = h;
  WlT[id] = __float2half_rn(v - __half2float(h));
}

// ---------------- MFMA GEMM: C = A @ B with split-fp16 operands ----------------
// acc = Ah*Bh + Ah*Bl (+ Al*Bh if NSPLIT==2), fp32 accum.
// Block = 128 rows x BN cols, 4 waves (2m x 2n); wave tile 64 x BN/2.
// MODE 0: half out = acc*aux[row]; MODE 1: half out = relu(acc+aux[col]); MODE 2: float out = acc+aux[col].

template<int BN, int MODE, int NSPLIT>
__global__ __launch_bounds__(256, (BN == 128) ? 3 : 4)
void k_mfma(const __half* __restrict__ Ah_g, const __half* __restrict__ Al_g,
            const __half* __restrict__ BhT_g, const __half* __restrict__ BlT_g,
            const float* __restrict__ aux, void* __restrict__ Cout,
            int M, int K, int ldc, int nRB) {
  constexpr int NR = BN / 32;
  constexpr int ALR = (NSPLIT == 2) ? 128 : 1;
  __shared__ __half Ahs[128][40];
  __shared__ __half Als[ALR][40];
  __shared__ __half Bhs[BN][40];
  __shared__ __half Bls[BN][40];

  const int t = threadIdx.x;
  const int rb = blockIdx.x % nRB, cb = blockIdx.x / nRB;
  const int rbase = rb * 128, cbase = cb * BN;
  const int lane = t & 63, wid = t >> 6;
  const int wr = (wid >> 1) * 64;
  const int wc = (wid & 1) * (BN / 2);
  const int lr = lane & 15, lq = lane >> 4;

  f32x4 acc[4][NR];
  #pragma unroll
  for (int m = 0; m < 4; ++m)
    #pragma unroll
    for (int n = 0; n < NR; ++n) acc[m][n] = (f32x4){0.f, 0.f, 0.f, 0.f};

  for (int kc = 0; kc < K; kc += 32) {
    __syncthreads();
    #pragma unroll
    for (int mm = 0; mm < 2; ++mm) {
      int idx = mm * 256 + t;
      int row = idx >> 2, q = idx & 3;
      int gr = rbase + row;
      uint4 vh = {0, 0, 0, 0};
      if (gr < M) vh = *(const uint4*)(Ah_g + (size_t)gr * K + kc + q * 8);
      *(uint4*)&Ahs[row][q * 8] = vh;
      if constexpr (NSPLIT == 2) {
        uint4 vl = {0, 0, 0, 0};
        if (gr < M) vl = *(const uint4*)(Al_g + (size_t)gr * K + kc + q * 8);
        *(uint4*)&Als[row][q * 8] = vl;
      }
    }
    #pragma unroll
    for (int mm = 0; mm < BN / 64; ++mm) {
      int idx = mm * 256 + t;
      int c = idx >> 2, q = idx & 3;
      size_t src = (size_t)(cbase + c) * K + kc + q * 8;
      *(uint4*)&Bhs[c][q * 8] = *(const uint4*)(BhT_g + src);
      *(uint4*)&Bls[c][q * 8] = *(const uint4*)(BlT_g + src);
    }
    __syncthreads();

    f16x8 fb[NR], fbl[NR], fa[4];
    #pragma unroll
    for (int n = 0; n < NR; ++n) {
      fb[n]  = *(const f16x8*)&Bhs[wc + n * 16 + lr][lq * 8];
      fbl[n] = *(const f16x8*)&Bls[wc + n * 16 + lr][lq * 8];
    }
    #pragma unroll
    for (int m = 0; m < 4; ++m)
      fa[m] = *(const f16x8*)&Ahs[wr + m * 16 + lr][lq * 8];

    #pragma unroll
    for (int m = 0; m < 4; ++m)
      #pragma unroll
      for (int n = 0; n < NR; ++n) {
        acc[m][n] = __builtin_amdgcn_mfma_f32_16x16x32_f16(fa[m], fb[n], acc[m][n], 0, 0, 0);
        acc[m][n] = __builtin_amdgcn_mfma_f32_16x16x32_f16(fa[m], fbl[n], acc[m][n], 0, 0, 0);
      }

    if constexpr (NSPLIT == 2) {
      f16x8 fal[4];
      #pragma unroll
      for (int m = 0; m < 4; ++m)
        fal[m] = *(const f16x8*)&Als[wr + m * 16 + lr][lq * 8];
      #pragma unroll
      for (int m = 0; m < 4; ++m)
        #pragma unroll
        for (int n = 0; n < NR; ++n)
          acc[m][n] = __builtin_amdgcn_mfma_f32_16x16x32_f16(fal[m], fb[n], acc[m][n], 0, 0, 0);
    }
  }

  if constexpr (MODE == 0) {
    __half* Yo = (__half*)Cout;
    #pragma unroll
    for (int m = 0; m < 4; ++m)
      #pragma unroll
      for (int j = 0; j < 4; ++j) {
        int row = rbase + wr + m * 16 + lq * 4 + j;
        if (row < M) {
          float s = aux[row];
          #pragma unroll
          for (int n = 0; n < NR; ++n) {
            int colg = cbase + wc + n * 16 + lr;
            Yo[(size_t)row * ldc + colg] = __float2half_rn(acc[m][n][j] * s);
          }
        }
      }
  } else {
    float bb[NR];
    #pragma unroll
    for (int n = 0; n < NR; ++n) bb[n] = aux[cbase + wc + n * 16 + lr];
    if constexpr (MODE == 1) {
      __half* Yo = (__half*)Cout;
      #pragma unroll
      for (int m = 0; m < 4; ++m)
        #pragma unroll
        for (int j = 0; j < 4; ++j) {
          int row = rbase + wr + m * 16 + lq * 4 + j;
          if (row < M) {
            #pragma unroll
            for (int n = 0; n < NR; ++n) {
              int colg = cbase + wc + n * 16 + lr;
              Yo[(size_t)row * ldc + colg] = __float2half_rn(fmaxf(acc[m][n][j] + bb[n], 0.f));
            }
          }
        }
    } else {
      float* Of = (float*)Cout;
      #pragma unroll
      for (int m = 0; m < 4; ++m)
        #pragma unroll
        for (int j = 0; j < 4; ++j) {
          int row = rbase + wr + m * 16 + lq * 4 + j;
          if (row < M) {
            #pragma unroll
            for (int n = 0; n < NR; ++n) {
              int colg = cbase + wc + n * 16 + lr;
              Of[(size_t)row * ldc + colg] = acc[m][n][j] + bb[n];
            }
          }
        }
    }
  }
}

// ---------------- aggregate: X' = relu(norm[i]*(y_i + sum y_src) + b), split output ----------------

__global__ __launch_bounds__(256) void k_agg(const __half* __restrict__ Y,
                                             const int* __restrict__ rowptr, const int* __restrict__ col,
                                             const float* __restrict__ nrm, const float* __restrict__ bias,
                                             __half2* __restrict__ Xh2, __half2* __restrict__ Xl2, int n) {
  int wid = (blockIdx.x * 256 + threadIdx.x) >> 6;
  int lane = threadIdx.x & 63;
  if (wid >= n) return;
  const __half2* Yv = (const __half2*)Y;
  float2 s0 = __half22float2(Yv[(size_t)wid * 64 + lane]);
  float2 s1 = make_float2(0.f, 0.f);
  float2 s2 = make_float2(0.f, 0.f);
  float2 s3 = make_float2(0.f, 0.f);
  int e0 = rowptr[wid], e1 = rowptr[wid + 1];
  int e = e0;
  for (; e + 4 <= e1; e += 4) {
    int c0 = col[e], c1 = col[e + 1], c2 = col[e + 2], c3 = col[e + 3];
    float2 v0 = __half22float2(Yv[(size_t)c0 * 64 + lane]);
    float2 v1 = __half22float2(Yv[(size_t)c1 * 64 + lane]);
    float2 v2 = __half22float2(Yv[(size_t)c2 * 64 + lane]);
    float2 v3 = __half22float2(Yv[(size_t)c3 * 64 + lane]);
    s0.x += v0.x; s0.y += v0.y;
    s1.x += v1.x; s1.y += v1.y;
    s2.x += v2.x; s2.y += v2.y;
    s3.x += v3.x; s3.y += v3.y;
  }
  for (; e < e1; ++e) {
    int c = col[e];
    float2 v = __half22float2(Yv[(size_t)c * 64 + lane]);
    s0.x += v.x; s0.y += v.y;
  }
  float2 s;
  s.x = (s0.x + s1.x) + (s2.x + s3.x);
  s.y = (s0.y + s1.y) + (s2.y + s3.y);
  float nm = nrm[wid];
  float2 bb = ((const float2*)bias)[lane];
  float ox = fmaxf(fmaf(s.x, nm, bb.x), 0.f);
  float oy = fmaxf(fmaf(s.y, nm, bb.y), 0.f);
  __half hx = __float2half_rn(ox), hy = __float2half_rn(oy);
  __half lx = __float2half_rn(ox - __half2float(hx));
  __half ly = __float2half_rn(oy - __half2float(hy));
  size_t idx = (size_t)wid * 64 + lane;
  Xh2[idx] = __halves2half2(hx, hy);
  Xl2[idx] = __halves2half2(lx, ly);
}

extern "C" void kernel_launch(void* const* d_in, const int* in_sizes, int n_in,
                              void* d_out, int out_size, void* d_ws, size_t ws_size,
                              hipStream_t stream) {
  const float* x     = (const float*)d_in[0];
  const int*   ei    = (const int*)d_in[1];
  const float* convW = (const float*)d_in[2];
  const float* convB = (const float*)d_in[3];
  const float* w1    = (const float*)d_in[4];
  const float* b1    = (const float*)d_in[5];
  const float* w2    = (const float*)d_in[6];
  const float* b2    = (const float*)d_in[7];
  float* out = (float*)d_out;

  int N = in_sizes[0] / D;
  int E = in_sizes[1] / 2;
  int L = in_sizes[2] / (D * D);
  int NBKT = (N + 255) >> 8;

  char* ws = (char*)d_ws;
  size_t off = 0;
  auto alloc = [&](size_t bytes) -> char* {
    char* p = ws + off;
    off += (bytes + 255) & ~(size_t)255;
    return p;
  };
  float*  nrm    = (float*)alloc((size_t)N * 4);
  int*    rowptr = (int*)alloc((size_t)(N + 1) * 4);
  int*    col    = (int*)alloc((size_t)E * 4);
  int*    bcnt   = (int*)alloc(512 * 4);
  int*    boff   = (int*)alloc(512 * 4);
  int*    bcur   = (int*)alloc(512 * 4);
  uint2*  bed    = (uint2*)alloc((size_t)E * 8);
  __half* Xh     = (__half*)alloc((size_t)N * D * 2);
  __half* Xl     = (__half*)alloc((size_t)N * D * 2);
  __half* Yh     = (__half*)alloc((size_t)N * D * 2);
  __half* Hh     = (__half*)alloc((size_t)N * FFN * 2);
  __half* WcTh   = (__half*)alloc((size_t)L * D * D * 2);
  __half* WcTl   = (__half*)alloc((size_t)L * D * D * 2);
  __half* W1Th   = (__half*)alloc((size_t)D * FFN * 2);
  __half* W1Tl   = (__half*)alloc((size_t)D * FFN * 2);
  __half* W2Th   = (__half*)alloc((size_t)FFN * BOT * 2);
  __half* W2Tl   = (__half*)alloc((size_t)FFN * BOT * 2);

  // ---- CSR build (bucketed counting sort) ----
  int gS = (E + EPB - 1) / EPB;
  hipMemsetAsync(bcnt, 0, 512 * 4, stream);
  k_bcnt<<<gS, 256, 0, stream>>>(ei + E, bcnt, E);       // dst half of edge_index
  k_bscan<<<1, 256, 0, stream>>>(bcnt, boff, bcur, NBKT, E);
  k_bscatter<<<gS, 256, 0, stream>>>(ei, bcur, bed, E);
  k_bcsr<<<NBKT, 256, 0, stream>>>(bed, boff, rowptr, nrm, col, N, E);

  // ---- operand prep ----
  int n8 = N * D / 8;
  k_split<<<(n8 + 255) / 256, 256, 0, stream>>>(x, Xh, Xl, n8);
  k_splitwc<<<(L * D * D + 255) / 256, 256, 0, stream>>>(convW, WcTh, WcTl, L * D * D);
  k_splitw<<<(D * FFN + 255) / 256, 256, 0, stream>>>(w1, W1Th, W1Tl, D, FFN);
  k_splitw<<<(FFN * BOT + 255) / 256, 256, 0, stream>>>(w2, W2Th, W2Tl, FFN, BOT);

  // ---- GCN layers ----
  int nRB = (N + 127) / 128;
  for (int l = 0; l < L; ++l) {
    k_mfma<128, 0, 2><<<nRB, 256, 0, stream>>>(
        Xh, Xl, WcTh + (size_t)l * D * D, WcTl + (size_t)l * D * D, nrm, Yh, N, D, D, nRB);
    k_agg<<<(N + 3) / 4, 256, 0, stream>>>(Yh, rowptr, col, nrm, convB + (size_t)l * D,
                                           (__half2*)Xh, (__half2*)Xl, N);
  }

  // ---- MLP ----
  k_mfma<128, 1, 2><<<nRB * (FFN / 128), 256, 0, stream>>>(
      Xh, Xl, W1Th, W1Tl, b1, Hh, N, D, FFN, nRB);
  k_mfma<64, 2, 1><<<nRB, 256, 0, stream>>>(
      Hh, (const __half*)nullptr, W2Th, W2Tl, b2, out, N, FFN, BOT, nRB);
}

// Round 9
// 270.988 us; speedup vs baseline: 2.7478x; 1.0419x over previous
//
#include <hip/hip_runtime.h>
#include <hip/hip_fp16.h>

#define D 128
#define FFN 512
#define BOT 64
#define EPB 4096      // edges per bucketing block

typedef _Float16 f16x8 __attribute__((ext_vector_type(8)));
typedef float f32x4 __attribute__((ext_vector_type(4)));

// ================ CSR build via bucketed counting sort ================

__global__ __launch_bounds__(256) void k_bcnt(const int* __restrict__ dst, int* __restrict__ bcnt, int nE) {
  __shared__ int h[256];
  int t = threadIdx.x;
  h[t] = 0;
  __syncthreads();
  int base = blockIdx.x * EPB;
  #pragma unroll
  for (int m = 0; m < EPB / 256; ++m) {
    int idx = base + m * 256 + t;
    if (idx < nE) atomicAdd(&h[dst[idx] >> 8], 1);
  }
  __syncthreads();
  if (h[t] > 0) atomicAdd(&bcnt[t], h[t]);
}

__global__ __launch_bounds__(256) void k_bscan(const int* __restrict__ bcnt, int* __restrict__ boff,
                                               int* __restrict__ bcur, int nbkt, int nE) {
  __shared__ int s[256];
  int t = threadIdx.x;
  int v = (t < nbkt) ? bcnt[t] : 0;
  s[t] = v;
  __syncthreads();
  for (int d = 1; d < 256; d <<= 1) {
    int add = (t >= d) ? s[t - d] : 0;
    __syncthreads();
    s[t] += add;
    __syncthreads();
  }
  int ex = s[t] - v;
  boff[t] = ex;
  bcur[t] = ex;
  if (t == 255) boff[256] = nE;
  if (t >= nbkt) boff[t] = nE;
}

__global__ __launch_bounds__(256) void k_bscatter(const int* __restrict__ ei, int* __restrict__ bcur,
                                                  uint2* __restrict__ bed, int nE) {
  __shared__ uint2 st[EPB];
  __shared__ int cnt[256], off[256], base[256], cur[256];
  int t = threadIdx.x;
  int blk0 = blockIdx.x * EPB;
  int nblk = nE - blk0;
  if (nblk > EPB) nblk = EPB;

  cnt[t] = 0;
  cur[t] = 0;
  __syncthreads();

  int rs[EPB / 256], rd[EPB / 256];
  #pragma unroll
  for (int m = 0; m < EPB / 256; ++m) {
    int idx = blk0 + m * 256 + t;
    if (idx < nE) {
      rs[m] = ei[idx];
      rd[m] = ei[nE + idx];
      atomicAdd(&cnt[rd[m] >> 8], 1);
    } else {
      rd[m] = -1;
    }
  }
  __syncthreads();

  int v = cnt[t];
  off[t] = v;
  __syncthreads();
  for (int d = 1; d < 256; d <<= 1) {
    int add = (t >= d) ? off[t - d] : 0;
    __syncthreads();
    off[t] += add;
    __syncthreads();
  }
  int ex = off[t] - v;
  __syncthreads();
  off[t] = ex;
  base[t] = (v > 0) ? atomicAdd(&bcur[t], v) : 0;
  __syncthreads();

  #pragma unroll
  for (int m = 0; m < EPB / 256; ++m) {
    if (rd[m] >= 0) {
      int b = rd[m] >> 8;
      int p = off[b] + atomicAdd(&cur[b], 1);
      st[p] = make_uint2((unsigned)rs[m], (unsigned)rd[m]);
    }
  }
  __syncthreads();

  for (int j = t; j < nblk; j += 256) {
    uint2 pr = st[j];
    int b = (int)(pr.y >> 8);
    bed[base[b] + (j - off[b])] = pr;
  }
}

__global__ __launch_bounds__(256) void k_bcsr(const uint2* __restrict__ bed, const int* __restrict__ boff,
                                              int* __restrict__ rowptr, float* __restrict__ nrm,
                                              int* __restrict__ col, int N, int nE) {
  __shared__ int cnt[256], noff[256], cur[256];
  int t = threadIdx.x;
  int b = blockIdx.x;
  int e0 = boff[b], e1 = boff[b + 1];

  cnt[t] = 0;
  __syncthreads();
  for (int j = e0 + t; j < e1; j += 256)
    atomicAdd(&cnt[bed[j].y & 255], 1);
  __syncthreads();

  int v = cnt[t];
  noff[t] = v;
  __syncthreads();
  for (int d = 1; d < 256; d <<= 1) {
    int add = (t >= d) ? noff[t - d] : 0;
    __syncthreads();
    noff[t] += add;
    __syncthreads();
  }
  int ex = noff[t] - v;
  __syncthreads();
  noff[t] = ex;
  cur[t] = ex;
  __syncthreads();

  int node = (b << 8) + t;
  if (node < N) {
    rowptr[node] = e0 + ex;
    nrm[node] = rsqrtf((float)v + 1.0f);
  }
  if (b == 0 && t == 0) rowptr[N] = nE;

  for (int j = e0 + t; j < e1; j += 256) {
    uint2 pr = bed[j];
    int d2 = (int)(pr.y & 255);
    int p = atomicAdd(&cur[d2], 1);
    col[e0 + p] = (int)pr.x;
  }
}

// ---------------- split helpers ----------------

__global__ __launch_bounds__(256) void k_split(const float* __restrict__ X,
                                               __half* __restrict__ Xh, __half* __restrict__ Xl, int n8) {
  int i = blockIdx.x * 256 + threadIdx.x;
  if (i >= n8) return;
  float4 a = ((const float4*)X)[i * 2];
  float4 b = ((const float4*)X)[i * 2 + 1];
  float v[8] = {a.x, a.y, a.z, a.w, b.x, b.y, b.z, b.w};
  __half2 hh[4], ll[4];
  #pragma unroll
  for (int q = 0; q < 4; ++q) {
    __half h0 = __float2half_rn(v[2 * q]);
    __half h1 = __float2half_rn(v[2 * q + 1]);
    __half l0 = __float2half_rn(v[2 * q] - __half2float(h0));
    __half l1 = __float2half_rn(v[2 * q + 1] - __half2float(h1));
    hh[q] = __halves2half2(h0, h1);
    ll[q] = __halves2half2(l0, l1);
  }
  *(uint4*)(Xh + (size_t)i * 8) = *(uint4*)hh;
  *(uint4*)(Xl + (size_t)i * 8) = *(uint4*)ll;
}

__global__ __launch_bounds__(256) void k_splitw(const float* __restrict__ W,
                                                __half* __restrict__ WhT, __half* __restrict__ WlT,
                                                int K, int N) {
  int id = blockIdx.x * 256 + threadIdx.x;
  if (id >= K * N) return;
  int n = id / K, k = id % K;
  float v = W[(size_t)k * N + n];
  __half h = __float2half_rn(v);
  WhT[id] = h;
  WlT[id] = __float2half_rn(v - __half2float(h));
}

__global__ __launch_bounds__(256) void k_splitwc(const float* __restrict__ W,
                                                 __half* __restrict__ WhT, __half* __restrict__ WlT,
                                                 int total) {
  int id = blockIdx.x * 256 + threadIdx.x;
  if (id >= total) return;
  int l = id / (D * D), r = id % (D * D);
  int n = r / D, k = r % D;
  float v = W[(size_t)l * D * D + (size_t)k * D + n];
  __half h = __float2half_rn(v);
  WhT[id] = h;
  WlT[id] = __float2half_rn(v - __half2float(h));
}

// ---------------- conv GEMM: Y = (X @ W) * nrm[row], split-fp16 MFMA ----------------
// 64-row blocks, BN=128 (full D). 4 waves: 2m x 2n; wave tile 32 x 64 (m-frags 2, n-frags 4).

__global__ __launch_bounds__(256, 4)
void k_conv(const __half* __restrict__ Ah_g, const __half* __restrict__ Al_g,
            const __half* __restrict__ BhT_g, const __half* __restrict__ BlT_g,
            const float* __restrict__ aux, __half* __restrict__ Yo, int M) {
  __shared__ __half Ahs[64][40];
  __shared__ __half Als[64][40];
  __shared__ __half Bhs[128][40];
  __shared__ __half Bls[128][40];

  const int t = threadIdx.x;
  const int rbase = blockIdx.x * 64;
  const int lane = t & 63, wid = t >> 6;
  const int wr = (wid >> 1) * 32;
  const int wc = (wid & 1) * 64;
  const int lr = lane & 15, lq = lane >> 4;

  f32x4 acc[2][4];
  #pragma unroll
  for (int m = 0; m < 2; ++m)
    #pragma unroll
    for (int n = 0; n < 4; ++n) acc[m][n] = (f32x4){0.f, 0.f, 0.f, 0.f};

  for (int kc = 0; kc < D; kc += 32) {
    __syncthreads();
    {
      int row = t >> 2, q = t & 3;
      int gr = rbase + row;
      uint4 vh = {0, 0, 0, 0}, vl = {0, 0, 0, 0};
      if (gr < M) {
        vh = *(const uint4*)(Ah_g + (size_t)gr * D + kc + q * 8);
        vl = *(const uint4*)(Al_g + (size_t)gr * D + kc + q * 8);
      }
      *(uint4*)&Ahs[row][q * 8] = vh;
      *(uint4*)&Als[row][q * 8] = vl;
    }
    #pragma unroll
    for (int mm = 0; mm < 2; ++mm) {
      int idx = mm * 256 + t;
      int c = idx >> 2, q = idx & 3;
      size_t src = (size_t)c * D + kc + q * 8;
      *(uint4*)&Bhs[c][q * 8] = *(const uint4*)(BhT_g + src);
      *(uint4*)&Bls[c][q * 8] = *(const uint4*)(BlT_g + src);
    }
    __syncthreads();

    f16x8 fa[2], fal[2], fb[4], fbl[4];
    #pragma unroll
    for (int m = 0; m < 2; ++m) {
      fa[m]  = *(const f16x8*)&Ahs[wr + m * 16 + lr][lq * 8];
      fal[m] = *(const f16x8*)&Als[wr + m * 16 + lr][lq * 8];
    }
    #pragma unroll
    for (int n = 0; n < 4; ++n) {
      fb[n]  = *(const f16x8*)&Bhs[wc + n * 16 + lr][lq * 8];
      fbl[n] = *(const f16x8*)&Bls[wc + n * 16 + lr][lq * 8];
    }
    #pragma unroll
    for (int m = 0; m < 2; ++m)
      #pragma unroll
      for (int n = 0; n < 4; ++n) {
        acc[m][n] = __builtin_amdgcn_mfma_f32_16x16x32_f16(fa[m], fb[n], acc[m][n], 0, 0, 0);
        acc[m][n] = __builtin_amdgcn_mfma_f32_16x16x32_f16(fa[m], fbl[n], acc[m][n], 0, 0, 0);
        acc[m][n] = __builtin_amdgcn_mfma_f32_16x16x32_f16(fal[m], fb[n], acc[m][n], 0, 0, 0);
      }
  }

  #pragma unroll
  for (int m = 0; m < 2; ++m)
    #pragma unroll
    for (int j = 0; j < 4; ++j) {
      int row = rbase + wr + m * 16 + lq * 4 + j;
      if (row < M) {
        float s = aux[row];
        #pragma unroll
        for (int n = 0; n < 4; ++n) {
          int colg = wc + n * 16 + lr;
          Yo[(size_t)row * D + colg] = __float2half_rn(acc[m][n][j] * s);
        }
      }
    }
}

// ---------------- fused MLP: Out = relu(X@W1+b1)@W2 + b2, MFMA ----------------
// 64-row blocks. 8 FFN chunks of 64. Per chunk: split-MFMA -> H fp16 in LDS -> MFMA vs split-W2.
// 4 waves 2m x 2n; fc1 wave tile 32x32; fc2 wave tile 32x32. LDS = 50 KB -> 3 blocks/CU.

__global__ __launch_bounds__(256, 3)
void k_mlp(const __half* __restrict__ Xh_g, const __half* __restrict__ Xl_g,
           const __half* __restrict__ W1hT, const __half* __restrict__ W1lT,
           const float* __restrict__ B1,
           const __half* __restrict__ W2hT, const __half* __restrict__ W2lT,
           const float* __restrict__ B2,
           float* __restrict__ Out, int M) {
  __shared__ __half Xhs[64][40], Xls[64][40];
  __shared__ __half W1hs[64][40], W1ls[64][40];
  __shared__ __half Hs[2][64][40];
  __shared__ __half W2hs[2][64][40], W2ls[2][64][40];

  const int t = threadIdx.x;
  const int rbase = blockIdx.x * 64;
  const int lane = t & 63, wid = t >> 6;
  const int wr = (wid >> 1) * 32;
  const int wcn = (wid & 1) * 32;       // n-offset for both fc1 (ffn) and fc2 (bot)
  const int lr = lane & 15, lq = lane >> 4;

  f32x4 accO[2][2];
  #pragma unroll
  for (int m = 0; m < 2; ++m)
    #pragma unroll
    for (int n = 0; n < 2; ++n) accO[m][n] = (f32x4){0.f, 0.f, 0.f, 0.f};

  for (int ch = 0; ch < FFN / 64; ++ch) {
    // ---- fc1: H-chunk = X @ W1[:, ch*64..+64] ----
    f32x4 accH[2][2];
    #pragma unroll
    for (int m = 0; m < 2; ++m)
      #pragma unroll
      for (int n = 0; n < 2; ++n) accH[m][n] = (f32x4){0.f, 0.f, 0.f, 0.f};

    for (int kc = 0; kc < D; kc += 32) {
      __syncthreads();
      {
        int row = t >> 2, q = t & 3;
        int gr = rbase + row;
        uint4 vh = {0, 0, 0, 0}, vl = {0, 0, 0, 0};
        if (gr < M) {
          vh = *(const uint4*)(Xh_g + (size_t)gr * D + kc + q * 8);
          vl = *(const uint4*)(Xl_g + (size_t)gr * D + kc + q * 8);
        }
        *(uint4*)&Xhs[row][q * 8] = vh;
        *(uint4*)&Xls[row][q * 8] = vl;
      }
      {
        int c = t >> 2, q = t & 3;
        size_t src = (size_t)(ch * 64 + c) * D + kc + q * 8;
        *(uint4*)&W1hs[c][q * 8] = *(const uint4*)(W1hT + src);
        *(uint4*)&W1ls[c][q * 8] = *(const uint4*)(W1lT + src);
      }
      __syncthreads();

      f16x8 fa[2], fal[2], fb[2], fbl[2];
      #pragma unroll
      for (int m = 0; m < 2; ++m) {
        fa[m]  = *(const f16x8*)&Xhs[wr + m * 16 + lr][lq * 8];
        fal[m] = *(const f16x8*)&Xls[wr + m * 16 + lr][lq * 8];
      }
      #pragma unroll
      for (int n = 0; n < 2; ++n) {
        fb[n]  = *(const f16x8*)&W1hs[wcn + n * 16 + lr][lq * 8];
        fbl[n] = *(const f16x8*)&W1ls[wcn + n * 16 + lr][lq * 8];
      }
      #pragma unroll
      for (int m = 0; m < 2; ++m)
        #pragma unroll
        for (int n = 0; n < 2; ++n) {
          accH[m][n] = __builtin_amdgcn_mfma_f32_16x16x32_f16(fa[m], fb[n], accH[m][n], 0, 0, 0);
          accH[m][n] = __builtin_amdgcn_mfma_f32_16x16x32_f16(fa[m], fbl[n], accH[m][n], 0, 0, 0);
          accH[m][n] = __builtin_amdgcn_mfma_f32_16x16x32_f16(fal[m], fb[n], accH[m][n], 0, 0, 0);
        }
    }

    // ---- relu + b1 -> Hs (fp16); stage W2 chunk ----
    __syncthreads();   // previous chunk's fc2 reads of Hs/W2 done
    {
      float bb1[2];
      #pragma unroll
      for (int n = 0; n < 2; ++n) bb1[n] = B1[ch * 64 + wcn + n * 16 + lr];
      #pragma unroll
      for (int m = 0; m < 2; ++m)
        #pragma unroll
        for (int n = 0; n < 2; ++n)
          #pragma unroll
          for (int j = 0; j < 4; ++j) {
            int rl = wr + m * 16 + lq * 4 + j;
            int cl = wcn + n * 16 + lr;
            Hs[cl >> 5][rl][cl & 31] = __float2half_rn(fmaxf(accH[m][n][j] + bb1[n], 0.f));
          }
    }
    #pragma unroll
    for (int s = 0; s < 2; ++s) {
      int c = t >> 2, q = t & 3;
      size_t src = (size_t)c * FFN + ch * 64 + s * 32 + q * 8;
      *(uint4*)&W2hs[s][c][q * 8] = *(const uint4*)(W2hT + src);
      *(uint4*)&W2ls[s][c][q * 8] = *(const uint4*)(W2lT + src);
    }
    __syncthreads();

    // ---- fc2: Out += H-chunk @ W2[ch*64..+64, :] ----
    #pragma unroll
    for (int s = 0; s < 2; ++s) {
      f16x8 fha[2], fwb[2], fwbl[2];
      #pragma unroll
      for (int m = 0; m < 2; ++m)
        fha[m] = *(const f16x8*)&Hs[s][wr + m * 16 + lr][lq * 8];
      #pragma unroll
      for (int n = 0; n < 2; ++n) {
        fwb[n]  = *(const f16x8*)&W2hs[s][wcn + n * 16 + lr][lq * 8];
        fwbl[n] = *(const f16x8*)&W2ls[s][wcn + n * 16 + lr][lq * 8];
      }
      #pragma unroll
      for (int m = 0; m < 2; ++m)
        #pragma unroll
        for (int n = 0; n < 2; ++n) {
          accO[m][n] = __builtin_amdgcn_mfma_f32_16x16x32_f16(fha[m], fwb[n], accO[m][n], 0, 0, 0);
          accO[m][n] = __builtin_amdgcn_mfma_f32_16x16x32_f16(fha[m], fwbl[n], accO[m][n], 0, 0, 0);
        }
    }
  }

  // epilogue: Out += b2
  #pragma unroll
  for (int m = 0; m < 2; ++m)
    #pragma unroll
    for (int j = 0; j < 4; ++j) {
      int row = rbase + wr + m * 16 + lq * 4 + j;
      if (row < M) {
        #pragma unroll
        for (int n = 0; n < 2; ++n) {
          int colg = wcn + n * 16 + lr;
          Out[(size_t)row * BOT + colg] = accO[m][n][j] + B2[colg];
        }
      }
    }
}

// ---------------- aggregate: X' = relu(norm[i]*(y_i + sum y_src) + b), split output ----------------
// 32-lane sub-groups: 1 node per 32 lanes, 8B (4ch) per lane.

__global__ __launch_bounds__(256) void k_agg(const __half* __restrict__ Y,
                                             const int* __restrict__ rowptr, const int* __restrict__ col,
                                             const float* __restrict__ nrm, const float* __restrict__ bias,
                                             __half* __restrict__ Xh, __half* __restrict__ Xl, int n) {
  int gtid = blockIdx.x * 256 + threadIdx.x;
  int node = gtid >> 5;
  int sl = threadIdx.x & 31;
  if (node >= n) return;
  const uint2* Yv = (const uint2*)Y;   // 4 f16 per uint2, 32 per row

  auto up = [](uint2 v, float4& a) {
    __half2 h0 = *(__half2*)&v.x, h1 = *(__half2*)&v.y;
    float2 f0 = __half22float2(h0), f1 = __half22float2(h1);
    a.x += f0.x; a.y += f0.y; a.z += f1.x; a.w += f1.y;
  };

  float4 s0 = {0.f, 0.f, 0.f, 0.f}, s1 = {0.f, 0.f, 0.f, 0.f};
  float4 s2 = {0.f, 0.f, 0.f, 0.f}, s3 = {0.f, 0.f, 0.f, 0.f};
  up(Yv[(size_t)node * 32 + sl], s0);          // self term
  int e0 = rowptr[node], e1 = rowptr[node + 1];
  int e = e0;
  for (; e + 4 <= e1; e += 4) {
    int c0 = col[e], c1 = col[e + 1], c2 = col[e + 2], c3 = col[e + 3];
    uint2 v0 = Yv[(size_t)c0 * 32 + sl];
    uint2 v1 = Yv[(size_t)c1 * 32 + sl];
    uint2 v2 = Yv[(size_t)c2 * 32 + sl];
    uint2 v3 = Yv[(size_t)c3 * 32 + sl];
    up(v0, s0); up(v1, s1); up(v2, s2); up(v3, s3);
  }
  for (; e < e1; ++e) up(Yv[(size_t)col[e] * 32 + sl], s0);

  float4 s;
  s.x = (s0.x + s1.x) + (s2.x + s3.x);
  s.y = (s0.y + s1.y) + (s2.y + s3.y);
  s.z = (s0.z + s1.z) + (s2.z + s3.z);
  s.w = (s0.w + s1.w) + (s2.w + s3.w);

  float nm = nrm[node];
  float4 bb = ((const float4*)bias)[sl];
  float o[4];
  o[0] = fmaxf(fmaf(s.x, nm, bb.x), 0.f);
  o[1] = fmaxf(fmaf(s.y, nm, bb.y), 0.f);
  o[2] = fmaxf(fmaf(s.z, nm, bb.z), 0.f);
  o[3] = fmaxf(fmaf(s.w, nm, bb.w), 0.f);

  __half h[4], l[4];
  #pragma unroll
  for (int q = 0; q < 4; ++q) {
    h[q] = __float2half_rn(o[q]);
    l[q] = __float2half_rn(o[q] - __half2float(h[q]));
  }
  uint2 ph, pl;
  ph.x = *(unsigned*)&(*(__half2*)&h[0]);
  __half2 h23 = __halves2half2(h[2], h[3]);
  ph.y = *(unsigned*)&h23;
  __half2 l01 = __halves2half2(l[0], l[1]);
  __half2 l23 = __halves2half2(l[2], l[3]);
  pl.x = *(unsigned*)&l01;
  pl.y = *(unsigned*)&l23;
  __half2 h01 = __halves2half2(h[0], h[1]);
  ph.x = *(unsigned*)&h01;
  ((uint2*)Xh)[(size_t)node * 32 + sl] = ph;
  ((uint2*)Xl)[(size_t)node * 32 + sl] = pl;
}

extern "C" void kernel_launch(void* const* d_in, const int* in_sizes, int n_in,
                              void* d_out, int out_size, void* d_ws, size_t ws_size,
                              hipStream_t stream) {
  const float* x     = (const float*)d_in[0];
  const int*   ei    = (const int*)d_in[1];
  const float* convW = (const float*)d_in[2];
  const float* convB = (const float*)d_in[3];
  const float* w1    = (const float*)d_in[4];
  const float* b1    = (const float*)d_in[5];
  const float* w2    = (const float*)d_in[6];
  const float* b2    = (const float*)d_in[7];
  float* out = (float*)d_out;

  int N = in_sizes[0] / D;
  int E = in_sizes[1] / 2;
  int L = in_sizes[2] / (D * D);
  int NBKT = (N + 255) >> 8;

  char* ws = (char*)d_ws;
  size_t off = 0;
  auto alloc = [&](size_t bytes) -> char* {
    char* p = ws + off;
    off += (bytes + 255) & ~(size_t)255;
    return p;
  };
  float*  nrm    = (float*)alloc((size_t)N * 4);
  int*    rowptr = (int*)alloc((size_t)(N + 1) * 4);
  int*    col    = (int*)alloc((size_t)E * 4);
  int*    bcnt   = (int*)alloc(512 * 4);
  int*    boff   = (int*)alloc(512 * 4);
  int*    bcur   = (int*)alloc(512 * 4);
  uint2*  bed    = (uint2*)alloc((size_t)E * 8);
  __half* Xh     = (__half*)alloc((size_t)N * D * 2);
  __half* Xl     = (__half*)alloc((size_t)N * D * 2);
  __half* Yh     = (__half*)alloc((size_t)N * D * 2);
  __half* WcTh   = (__half*)alloc((size_t)L * D * D * 2);
  __half* WcTl   = (__half*)alloc((size_t)L * D * D * 2);
  __half* W1Th   = (__half*)alloc((size_t)D * FFN * 2);
  __half* W1Tl   = (__half*)alloc((size_t)D * FFN * 2);
  __half* W2Th   = (__half*)alloc((size_t)FFN * BOT * 2);
  __half* W2Tl   = (__half*)alloc((size_t)FFN * BOT * 2);

  // ---- CSR build (bucketed counting sort) ----
  int gS = (E + EPB - 1) / EPB;
  hipMemsetAsync(bcnt, 0, 512 * 4, stream);
  k_bcnt<<<gS, 256, 0, stream>>>(ei + E, bcnt, E);
  k_bscan<<<1, 256, 0, stream>>>(bcnt, boff, bcur, NBKT, E);
  k_bscatter<<<gS, 256, 0, stream>>>(ei, bcur, bed, E);
  k_bcsr<<<NBKT, 256, 0, stream>>>(bed, boff, rowptr, nrm, col, N, E);

  // ---- operand prep ----
  int n8 = N * D / 8;
  k_split<<<(n8 + 255) / 256, 256, 0, stream>>>(x, Xh, Xl, n8);
  k_splitwc<<<(L * D * D + 255) / 256, 256, 0, stream>>>(convW, WcTh, WcTl, L * D * D);
  k_splitw<<<(D * FFN + 255) / 256, 256, 0, stream>>>(w1, W1Th, W1Tl, D, FFN);
  k_splitw<<<(FFN * BOT + 255) / 256, 256, 0, stream>>>(w2, W2Th, W2Tl, FFN, BOT);

  // ---- GCN layers ----
  int nRB = (N + 63) / 64;
  for (int l = 0; l < L; ++l) {
    k_conv<<<nRB, 256, 0, stream>>>(
        Xh, Xl, WcTh + (size_t)l * D * D, WcTl + (size_t)l * D * D, nrm, Yh, N);
    k_agg<<<(N * 32 + 255) / 256, 256, 0, stream>>>(Yh, rowptr, col, nrm, convB + (size_t)l * D,
                                                    Xh, Xl, N);
  }

  // ---- fused MLP ----
  k_mlp<<<nRB, 256, 0, stream>>>(Xh, Xl, W1Th, W1Tl, b1, W2Th, W2Tl, b2, out, N);
}

// Round 10
// 252.353 us; speedup vs baseline: 2.9507x; 1.0738x over previous
//
#include <hip/hip_runtime.h>
#include <hip/hip_fp16.h>

#define D 128
#define FFN 512
#define BOT 64
#define EPB 4096      // edges per bucketing block

typedef _Float16 f16x8 __attribute__((ext_vector_type(8)));
typedef float f32x4 __attribute__((ext_vector_type(4)));

// ================ CSR build via bucketed counting sort ================

__global__ __launch_bounds__(256) void k_bcnt(const int* __restrict__ dst, int* __restrict__ bcnt, int nE) {
  __shared__ int h[256];
  int t = threadIdx.x;
  h[t] = 0;
  __syncthreads();
  int base = blockIdx.x * EPB;
  #pragma unroll
  for (int m = 0; m < EPB / 256; ++m) {
    int idx = base + m * 256 + t;
    if (idx < nE) atomicAdd(&h[dst[idx] >> 8], 1);
  }
  __syncthreads();
  if (h[t] > 0) atomicAdd(&bcnt[t], h[t]);
}

__global__ __launch_bounds__(256) void k_bscan(const int* __restrict__ bcnt, int* __restrict__ boff,
                                               int* __restrict__ bcur, int nbkt, int nE) {
  __shared__ int s[256];
  int t = threadIdx.x;
  int v = (t < nbkt) ? bcnt[t] : 0;
  s[t] = v;
  __syncthreads();
  for (int d = 1; d < 256; d <<= 1) {
    int add = (t >= d) ? s[t - d] : 0;
    __syncthreads();
    s[t] += add;
    __syncthreads();
  }
  int ex = s[t] - v;
  boff[t] = ex;
  bcur[t] = ex;
  if (t == 255) boff[256] = nE;
  if (t >= nbkt) boff[t] = nE;
}

__global__ __launch_bounds__(256) void k_bscatter(const int* __restrict__ ei, int* __restrict__ bcur,
                                                  uint2* __restrict__ bed, int nE) {
  __shared__ uint2 st[EPB];
  __shared__ int cnt[256], off[256], base[256], cur[256];
  int t = threadIdx.x;
  int blk0 = blockIdx.x * EPB;
  int nblk = nE - blk0;
  if (nblk > EPB) nblk = EPB;

  cnt[t] = 0;
  cur[t] = 0;
  __syncthreads();

  int rs[EPB / 256], rd[EPB / 256];
  #pragma unroll
  for (int m = 0; m < EPB / 256; ++m) {
    int idx = blk0 + m * 256 + t;
    if (idx < nE) {
      rs[m] = ei[idx];
      rd[m] = ei[nE + idx];
      atomicAdd(&cnt[rd[m] >> 8], 1);
    } else {
      rd[m] = -1;
    }
  }
  __syncthreads();

  int v = cnt[t];
  off[t] = v;
  __syncthreads();
  for (int d = 1; d < 256; d <<= 1) {
    int add = (t >= d) ? off[t - d] : 0;
    __syncthreads();
    off[t] += add;
    __syncthreads();
  }
  int ex = off[t] - v;
  __syncthreads();
  off[t] = ex;
  base[t] = (v > 0) ? atomicAdd(&bcur[t], v) : 0;
  __syncthreads();

  #pragma unroll
  for (int m = 0; m < EPB / 256; ++m) {
    if (rd[m] >= 0) {
      int b = rd[m] >> 8;
      int p = off[b] + atomicAdd(&cur[b], 1);
      st[p] = make_uint2((unsigned)rs[m], (unsigned)rd[m]);
    }
  }
  __syncthreads();

  for (int j = t; j < nblk; j += 256) {
    uint2 pr = st[j];
    int b = (int)(pr.y >> 8);
    bed[base[b] + (j - off[b])] = pr;
  }
}

__global__ __launch_bounds__(256) void k_bcsr(const uint2* __restrict__ bed, const int* __restrict__ boff,
                                              int* __restrict__ rowptr, float* __restrict__ nrm,
                                              int* __restrict__ col, int N, int nE) {
  __shared__ int cnt[256], noff[256], cur[256];
  int t = threadIdx.x;
  int b = blockIdx.x;
  int e0 = boff[b], e1 = boff[b + 1];

  cnt[t] = 0;
  __syncthreads();
  for (int j = e0 + t; j < e1; j += 256)
    atomicAdd(&cnt[bed[j].y & 255], 1);
  __syncthreads();

  int v = cnt[t];
  noff[t] = v;
  __syncthreads();
  for (int d = 1; d < 256; d <<= 1) {
    int add = (t >= d) ? noff[t - d] : 0;
    __syncthreads();
    noff[t] += add;
    __syncthreads();
  }
  int ex = noff[t] - v;
  __syncthreads();
  noff[t] = ex;
  cur[t] = ex;
  __syncthreads();

  int node = (b << 8) + t;
  if (node < N) {
    rowptr[node] = e0 + ex;
    nrm[node] = rsqrtf((float)v + 1.0f);
  }
  if (b == 0 && t == 0) rowptr[N] = nE;

  for (int j = e0 + t; j < e1; j += 256) {
    uint2 pr = bed[j];
    int d2 = (int)(pr.y & 255);
    int p = atomicAdd(&cur[d2], 1);
    col[e0 + p] = (int)pr.x;
  }
}

// ---------------- split helpers ----------------

__global__ __launch_bounds__(256) void k_split(const float* __restrict__ X,
                                               __half* __restrict__ Xh, __half* __restrict__ Xl, int n8) {
  int i = blockIdx.x * 256 + threadIdx.x;
  if (i >= n8) return;
  float4 a = ((const float4*)X)[i * 2];
  float4 b = ((const float4*)X)[i * 2 + 1];
  float v[8] = {a.x, a.y, a.z, a.w, b.x, b.y, b.z, b.w};
  __half2 hh[4], ll[4];
  #pragma unroll
  for (int q = 0; q < 4; ++q) {
    __half h0 = __float2half_rn(v[2 * q]);
    __half h1 = __float2half_rn(v[2 * q + 1]);
    __half l0 = __float2half_rn(v[2 * q] - __half2float(h0));
    __half l1 = __float2half_rn(v[2 * q + 1] - __half2float(h1));
    hh[q] = __halves2half2(h0, h1);
    ll[q] = __halves2half2(l0, l1);
  }
  *(uint4*)(Xh + (size_t)i * 8) = *(uint4*)hh;
  *(uint4*)(Xl + (size_t)i * 8) = *(uint4*)ll;
}

__global__ __launch_bounds__(256) void k_splitw(const float* __restrict__ W,
                                                __half* __restrict__ WhT, __half* __restrict__ WlT,
                                                int K, int N) {
  int id = blockIdx.x * 256 + threadIdx.x;
  if (id >= K * N) return;
  int n = id / K, k = id % K;
  float v = W[(size_t)k * N + n];
  __half h = __float2half_rn(v);
  WhT[id] = h;
  WlT[id] = __float2half_rn(v - __half2float(h));
}

__global__ __launch_bounds__(256) void k_splitwc(const float* __restrict__ W,
                                                 __half* __restrict__ WhT, __half* __restrict__ WlT,
                                                 int total) {
  int id = blockIdx.x * 256 + threadIdx.x;
  if (id >= total) return;
  int l = id / (D * D), r = id % (D * D);
  int n = r / D, k = r % D;
  float v = W[(size_t)l * D * D + (size_t)k * D + n];
  __half h = __float2half_rn(v);
  WhT[id] = h;
  WlT[id] = __float2half_rn(v - __half2float(h));
}

// ---------------- conv GEMM: Y = (X @ W) * nrm[row], split-fp16 MFMA ----------------

__global__ __launch_bounds__(256, 4)
void k_conv(const __half* __restrict__ Ah_g, const __half* __restrict__ Al_g,
            const __half* __restrict__ BhT_g, const __half* __restrict__ BlT_g,
            const float* __restrict__ aux, __half* __restrict__ Yo, int M) {
  __shared__ __half Ahs[64][40];
  __shared__ __half Als[64][40];
  __shared__ __half Bhs[128][40];
  __shared__ __half Bls[128][40];

  const int t = threadIdx.x;
  const int rbase = blockIdx.x * 64;
  const int lane = t & 63, wid = t >> 6;
  const int wr = (wid >> 1) * 32;
  const int wc = (wid & 1) * 64;
  const int lr = lane & 15, lq = lane >> 4;

  f32x4 acc[2][4];
  #pragma unroll
  for (int m = 0; m < 2; ++m)
    #pragma unroll
    for (int n = 0; n < 4; ++n) acc[m][n] = (f32x4){0.f, 0.f, 0.f, 0.f};

  for (int kc = 0; kc < D; kc += 32) {
    __syncthreads();
    {
      int row = t >> 2, q = t & 3;
      int gr = rbase + row;
      uint4 vh = {0, 0, 0, 0}, vl = {0, 0, 0, 0};
      if (gr < M) {
        vh = *(const uint4*)(Ah_g + (size_t)gr * D + kc + q * 8);
        vl = *(const uint4*)(Al_g + (size_t)gr * D + kc + q * 8);
      }
      *(uint4*)&Ahs[row][q * 8] = vh;
      *(uint4*)&Als[row][q * 8] = vl;
    }
    #pragma unroll
    for (int mm = 0; mm < 2; ++mm) {
      int idx = mm * 256 + t;
      int c = idx >> 2, q = idx & 3;
      size_t src = (size_t)c * D + kc + q * 8;
      *(uint4*)&Bhs[c][q * 8] = *(const uint4*)(BhT_g + src);
      *(uint4*)&Bls[c][q * 8] = *(const uint4*)(BlT_g + src);
    }
    __syncthreads();

    f16x8 fa[2], fal[2], fb[4], fbl[4];
    #pragma unroll
    for (int m = 0; m < 2; ++m) {
      fa[m]  = *(const f16x8*)&Ahs[wr + m * 16 + lr][lq * 8];
      fal[m] = *(const f16x8*)&Als[wr + m * 16 + lr][lq * 8];
    }
    #pragma unroll
    for (int n = 0; n < 4; ++n) {
      fb[n]  = *(const f16x8*)&Bhs[wc + n * 16 + lr][lq * 8];
      fbl[n] = *(const f16x8*)&Bls[wc + n * 16 + lr][lq * 8];
    }
    #pragma unroll
    for (int m = 0; m < 2; ++m)
      #pragma unroll
      for (int n = 0; n < 4; ++n) {
        acc[m][n] = __builtin_amdgcn_mfma_f32_16x16x32_f16(fa[m], fb[n], acc[m][n], 0, 0, 0);
        acc[m][n] = __builtin_amdgcn_mfma_f32_16x16x32_f16(fa[m], fbl[n], acc[m][n], 0, 0, 0);
        acc[m][n] = __builtin_amdgcn_mfma_f32_16x16x32_f16(fal[m], fb[n], acc[m][n], 0, 0, 0);
      }
  }

  #pragma unroll
  for (int m = 0; m < 2; ++m)
    #pragma unroll
    for (int j = 0; j < 4; ++j) {
      int row = rbase + wr + m * 16 + lq * 4 + j;
      if (row < M) {
        float s = aux[row];
        #pragma unroll
        for (int n = 0; n < 4; ++n) {
          int colg = wc + n * 16 + lr;
          Yo[(size_t)row * D + colg] = __float2half_rn(acc[m][n][j] * s);
        }
      }
    }
}

// ---------------- fused MLP v2: Out = relu(X@W1+b1)@W2 + b2, MFMA ----------------
// 64-row blocks. X staged once (full K=128). Per 64-wide FFN chunk:
//   stage W1-chunk -> 48 barrier-free MFMAs (fc1) -> Hs -> stage W2-chunk into
//   the SAME buffer -> 16 MFMAs (fc2, accumulate Out in regs).
// 4 syncs/chunk (was ~10). LDS = 77 KB -> 2 blocks/CU.

__global__ __launch_bounds__(256, 2)
void k_mlp(const __half* __restrict__ Xh_g, const __half* __restrict__ Xl_g,
           const __half* __restrict__ W1hT, const __half* __restrict__ W1lT,
           const float* __restrict__ B1,
           const __half* __restrict__ W2hT, const __half* __restrict__ W2lT,
           const float* __restrict__ B2,
           float* __restrict__ Out, int M) {
  __shared__ __half Xhs[64][136], Xls[64][136];
  __shared__ __half Ws[2][64][136];     // W1 h/l chunk; reused for W2 h/l
  __shared__ __half Hs[64][72];

  const int t = threadIdx.x;
  const int rbase = blockIdx.x * 64;
  const int lane = t & 63, wid = t >> 6;
  const int wr = (wid >> 1) * 32;
  const int wcn = (wid & 1) * 32;
  const int lr = lane & 15, lq = lane >> 4;

  // stage X once, full K (4 uint4 per thread per array)
  #pragma unroll
  for (int mm = 0; mm < 4; ++mm) {
    int idx = mm * 256 + t;
    int row = idx >> 4, q = idx & 15;
    int gr = rbase + row;
    uint4 vh = {0, 0, 0, 0}, vl = {0, 0, 0, 0};
    if (gr < M) {
      vh = *(const uint4*)(Xh_g + (size_t)gr * D + q * 8);
      vl = *(const uint4*)(Xl_g + (size_t)gr * D + q * 8);
    }
    *(uint4*)&Xhs[row][q * 8] = vh;
    *(uint4*)&Xls[row][q * 8] = vl;
  }

  f32x4 accO[2][2];
  #pragma unroll
  for (int m = 0; m < 2; ++m)
    #pragma unroll
    for (int n = 0; n < 2; ++n) accO[m][n] = (f32x4){0.f, 0.f, 0.f, 0.f};

  for (int ch = 0; ch < FFN / 64; ++ch) {
    __syncthreads();   // (a) prior fc2 done with Ws/Hs; (first iter: X visible)
    // stage W1 chunk: 64 ffn-cols x 128 k
    #pragma unroll
    for (int mm = 0; mm < 4; ++mm) {
      int idx = mm * 256 + t;
      int c = idx >> 4, q = idx & 15;
      size_t src = (size_t)(ch * 64 + c) * D + q * 8;
      *(uint4*)&Ws[0][c][q * 8] = *(const uint4*)(W1hT + src);
      *(uint4*)&Ws[1][c][q * 8] = *(const uint4*)(W1lT + src);
    }
    __syncthreads();   // (b) W1 ready

    // ---- fc1: 48 MFMAs, no barrier ----
    f32x4 accH[2][2];
    #pragma unroll
    for (int m = 0; m < 2; ++m)
      #pragma unroll
      for (int n = 0; n < 2; ++n) accH[m][n] = (f32x4){0.f, 0.f, 0.f, 0.f};

    #pragma unroll
    for (int kf = 0; kf < 4; ++kf) {
      f16x8 fa[2], fal[2], fb[2], fbl[2];
      #pragma unroll
      for (int m = 0; m < 2; ++m) {
        fa[m]  = *(const f16x8*)&Xhs[wr + m * 16 + lr][kf * 32 + lq * 8];
        fal[m] = *(const f16x8*)&Xls[wr + m * 16 + lr][kf * 32 + lq * 8];
      }
      #pragma unroll
      for (int n = 0; n < 2; ++n) {
        fb[n]  = *(const f16x8*)&Ws[0][wcn + n * 16 + lr][kf * 32 + lq * 8];
        fbl[n] = *(const f16x8*)&Ws[1][wcn + n * 16 + lr][kf * 32 + lq * 8];
      }
      #pragma unroll
      for (int m = 0; m < 2; ++m)
        #pragma unroll
        for (int n = 0; n < 2; ++n) {
          accH[m][n] = __builtin_amdgcn_mfma_f32_16x16x32_f16(fa[m], fb[n], accH[m][n], 0, 0, 0);
          accH[m][n] = __builtin_amdgcn_mfma_f32_16x16x32_f16(fa[m], fbl[n], accH[m][n], 0, 0, 0);
          accH[m][n] = __builtin_amdgcn_mfma_f32_16x16x32_f16(fal[m], fb[n], accH[m][n], 0, 0, 0);
        }
    }

    // relu + b1 -> Hs
    {
      float bb1[2];
      #pragma unroll
      for (int n = 0; n < 2; ++n) bb1[n] = B1[ch * 64 + wcn + n * 16 + lr];
      #pragma unroll
      for (int m = 0; m < 2; ++m)
        #pragma unroll
        for (int n = 0; n < 2; ++n)
          #pragma unroll
          for (int j = 0; j < 4; ++j) {
            int rl = wr + m * 16 + lq * 4 + j;
            int cl = wcn + n * 16 + lr;
            Hs[rl][cl] = __float2half_rn(fmaxf(accH[m][n][j] + bb1[n], 0.f));
          }
    }
    __syncthreads();   // (c) Hs ready; fc1 done reading Ws
    // stage W2 chunk: 64 bot-cols x 64 k into same Ws region
    #pragma unroll
    for (int mm = 0; mm < 2; ++mm) {
      int idx = mm * 256 + t;
      int c = idx >> 3, q = idx & 7;
      size_t src = (size_t)c * FFN + ch * 64 + q * 8;
      *(uint4*)&Ws[0][c][q * 8] = *(const uint4*)(W2hT + src);
      *(uint4*)&Ws[1][c][q * 8] = *(const uint4*)(W2lT + src);
    }
    __syncthreads();   // (d) W2 ready

    // ---- fc2: 16 MFMAs ----
    #pragma unroll
    for (int s = 0; s < 2; ++s) {
      f16x8 fha[2], fwb[2], fwbl[2];
      #pragma unroll
      for (int m = 0; m < 2; ++m)
        fha[m] = *(const f16x8*)&Hs[wr + m * 16 + lr][s * 32 + lq * 8];
      #pragma unroll
      for (int n = 0; n < 2; ++n) {
        fwb[n]  = *(const f16x8*)&Ws[0][wcn + n * 16 + lr][s * 32 + lq * 8];
        fwbl[n] = *(const f16x8*)&Ws[1][wcn + n * 16 + lr][s * 32 + lq * 8];
      }
      #pragma unroll
      for (int m = 0; m < 2; ++m)
        #pragma unroll
        for (int n = 0; n < 2; ++n) {
          accO[m][n] = __builtin_amdgcn_mfma_f32_16x16x32_f16(fha[m], fwb[n], accO[m][n], 0, 0, 0);
          accO[m][n] = __builtin_amdgcn_mfma_f32_16x16x32_f16(fha[m], fwbl[n], accO[m][n], 0, 0, 0);
        }
    }
  }

  // epilogue: Out += b2
  #pragma unroll
  for (int m = 0; m < 2; ++m)
    #pragma unroll
    for (int j = 0; j < 4; ++j) {
      int row = rbase + wr + m * 16 + lq * 4 + j;
      if (row < M) {
        #pragma unroll
        for (int n = 0; n < 2; ++n) {
          int colg = wcn + n * 16 + lr;
          Out[(size_t)row * BOT + colg] = accO[m][n][j] + B2[colg];
        }
      }
    }
}

// ---------------- aggregate: X' = relu(norm[i]*(y_i + sum y_src) + b), split output ----------------
// 16-lane sub-groups: 1 node per 16 lanes, 16B (8ch) per lane.

__global__ __launch_bounds__(256) void k_agg(const __half* __restrict__ Y,
                                             const int* __restrict__ rowptr, const int* __restrict__ col,
                                             const float* __restrict__ nrm, const float* __restrict__ bias,
                                             __half* __restrict__ Xh, __half* __restrict__ Xl, int n) {
  int gtid = blockIdx.x * 256 + threadIdx.x;
  int node = gtid >> 4;
  int sl = threadIdx.x & 15;
  if (node >= n) return;
  const uint4* Yv = (const uint4*)Y;   // 8 f16 per uint4, 16 per row

  float s0[8] = {0.f, 0.f, 0.f, 0.f, 0.f, 0.f, 0.f, 0.f};
  float s1[8] = {0.f, 0.f, 0.f, 0.f, 0.f, 0.f, 0.f, 0.f};
  auto up = [](uint4 v, float* a) {
    __half2* hp = (__half2*)&v;
    #pragma unroll
    for (int q = 0; q < 4; ++q) {
      float2 f = __half22float2(hp[q]);
      a[2 * q] += f.x;
      a[2 * q + 1] += f.y;
    }
  };
  up(Yv[(size_t)node * 16 + sl], s0);          // self term
  int e0 = rowptr[node], e1 = rowptr[node + 1];
  int e = e0;
  for (; e + 4 <= e1; e += 4) {
    int c0 = col[e], c1 = col[e + 1], c2 = col[e + 2], c3 = col[e + 3];
    uint4 v0 = Yv[(size_t)c0 * 16 + sl];
    uint4 v1 = Yv[(size_t)c1 * 16 + sl];
    uint4 v2 = Yv[(size_t)c2 * 16 + sl];
    uint4 v3 = Yv[(size_t)c3 * 16 + sl];
    up(v0, s0); up(v1, s1); up(v2, s0); up(v3, s1);
  }
  for (; e < e1; ++e) up(Yv[(size_t)col[e] * 16 + sl], s0);

  float nm = nrm[node];
  const float* bp = bias + sl * 8;
  __half h[8], l[8];
  #pragma unroll
  for (int q = 0; q < 8; ++q) {
    float o = fmaxf(fmaf(s0[q] + s1[q], nm, bp[q]), 0.f);
    h[q] = __float2half_rn(o);
    l[q] = __float2half_rn(o - __half2float(h[q]));
  }
  ((uint4*)Xh)[(size_t)node * 16 + sl] = *(uint4*)h;
  ((uint4*)Xl)[(size_t)node * 16 + sl] = *(uint4*)l;
}

extern "C" void kernel_launch(void* const* d_in, const int* in_sizes, int n_in,
                              void* d_out, int out_size, void* d_ws, size_t ws_size,
                              hipStream_t stream) {
  const float* x     = (const float*)d_in[0];
  const int*   ei    = (const int*)d_in[1];
  const float* convW = (const float*)d_in[2];
  const float* convB = (const float*)d_in[3];
  const float* w1    = (const float*)d_in[4];
  const float* b1    = (const float*)d_in[5];
  const float* w2    = (const float*)d_in[6];
  const float* b2    = (const float*)d_in[7];
  float* out = (float*)d_out;

  int N = in_sizes[0] / D;
  int E = in_sizes[1] / 2;
  int L = in_sizes[2] / (D * D);
  int NBKT = (N + 255) >> 8;

  char* ws = (char*)d_ws;
  size_t off = 0;
  auto alloc = [&](size_t bytes) -> char* {
    char* p = ws + off;
    off += (bytes + 255) & ~(size_t)255;
    return p;
  };
  float*  nrm    = (float*)alloc((size_t)N * 4);
  int*    rowptr = (int*)alloc((size_t)(N + 1) * 4);
  int*    col    = (int*)alloc((size_t)E * 4);
  int*    bcnt   = (int*)alloc(512 * 4);
  int*    boff   = (int*)alloc(512 * 4);
  int*    bcur   = (int*)alloc(512 * 4);
  uint2*  bed    = (uint2*)alloc((size_t)E * 8);
  __half* Xh     = (__half*)alloc((size_t)N * D * 2);
  __half* Xl     = (__half*)alloc((size_t)N * D * 2);
  __half* Yh     = (__half*)alloc((size_t)N * D * 2);
  __half* WcTh   = (__half*)alloc((size_t)L * D * D * 2);
  __half* WcTl   = (__half*)alloc((size_t)L * D * D * 2);
  __half* W1Th   = (__half*)alloc((size_t)D * FFN * 2);
  __half* W1Tl   = (__half*)alloc((size_t)D * FFN * 2);
  __half* W2Th   = (__half*)alloc((size_t)FFN * BOT * 2);
  __half* W2Tl   = (__half*)alloc((size_t)FFN * BOT * 2);

  // ---- CSR build (bucketed counting sort) ----
  int gS = (E + EPB - 1) / EPB;
  hipMemsetAsync(bcnt, 0, 512 * 4, stream);
  k_bcnt<<<gS, 256, 0, stream>>>(ei + E, bcnt, E);
  k_bscan<<<1, 256, 0, stream>>>(bcnt, boff, bcur, NBKT, E);
  k_bscatter<<<gS, 256, 0, stream>>>(ei, bcur, bed, E);
  k_bcsr<<<NBKT, 256, 0, stream>>>(bed, boff, rowptr, nrm, col, N, E);

  // ---- operand prep ----
  int n8 = N * D / 8;
  k_split<<<(n8 + 255) / 256, 256, 0, stream>>>(x, Xh, Xl, n8);
  k_splitwc<<<(L * D * D + 255) / 256, 256, 0, stream>>>(convW, WcTh, WcTl, L * D * D);
  k_splitw<<<(D * FFN + 255) / 256, 256, 0, stream>>>(w1, W1Th, W1Tl, D, FFN);
  k_splitw<<<(FFN * BOT + 255) / 256, 256, 0, stream>>>(w2, W2Th, W2Tl, FFN, BOT);

  // ---- GCN layers ----
  int nRB = (N + 63) / 64;
  for (int l = 0; l < L; ++l) {
    k_conv<<<nRB, 256, 0, stream>>>(
        Xh, Xl, WcTh + (size_t)l * D * D, WcTl + (size_t)l * D * D, nrm, Yh, N);
    k_agg<<<(N * 16 + 255) / 256, 256, 0, stream>>>(Yh, rowptr, col, nrm, convB + (size_t)l * D,
                                                    Xh, Xl, N);
  }

  // ---- fused MLP ----
  k_mlp<<<nRB, 256, 0, stream>>>(Xh, Xl, W1Th, W1Tl, b1, W2Th, W2Tl, b2, out, N);
}